// Round 5
// baseline (12808.940 us; speedup 1.0000x reference)
//
#include <hip/hip_runtime.h>

// ---------------------------------------------------------------------------
// SQLDecoder: 48-step recurrent decoder, ONE persistent kernel for all steps.
//   * scores = src @ (h @ W_att); flash-style single-pass attention (K==V==src)
//   * src cached bf16, non-temporal reads (no reuse; protects weights in L3)
//   * bf16 MFMA everywhere; fp32 cell/readout
//   * phases A(gates+LSTM) B(q) C(flash) D(att) E(readout) with device-wide
//     barriers (atomic counter; all 256 blocks co-resident at 1 block/CU)
// B=256 S=512 E=H=AV=1024 A=TY=128 T=48 NP=97 K_state=2048 K_cat=2304
// ---------------------------------------------------------------------------

typedef short s16x8 __attribute__((ext_vector_type(8)));
typedef float f32x4 __attribute__((ext_vector_type(4)));

__device__ __forceinline__ unsigned short f2b(float x) {
  unsigned int u = __float_as_uint(x);
  return (unsigned short)((u + 0x7fffu + ((u >> 16) & 1u)) >> 16);  // RNE
}
__device__ __forceinline__ float b2f(unsigned short h) {
  return __uint_as_float(((unsigned int)h) << 16);
}
__device__ __forceinline__ float sigm(float x) { return 1.f / (1.f + __expf(-x)); }

// device-wide barrier: monotonic counter, all blocks co-resident
__device__ __forceinline__ void gbar(unsigned* cnt, unsigned target) {
  __syncthreads();
  if (threadIdx.x == 0) {
    __threadfence();  // release: drain this block's stores to device scope
    __hip_atomic_fetch_add(cnt, 1u, __ATOMIC_RELEASE, __HIP_MEMORY_SCOPE_AGENT);
    while (__hip_atomic_load(cnt, __ATOMIC_ACQUIRE, __HIP_MEMORY_SCOPE_AGENT) < target)
      __builtin_amdgcn_s_sleep(2);
    __threadfence();  // acquire: invalidate stale cached lines
  }
  __syncthreads();
}

// ---------------- prep kernels ----------------------------------------------

template <int WRITE_B16>
__global__ __launch_bounds__(256) void pool_convert(const float* __restrict__ src,
                                                    unsigned short* __restrict__ srcb,
                                                    unsigned short* __restrict__ pooledb) {
  int b = blockIdx.x >> 2;
  int e = (blockIdx.x & 3) * 256 + threadIdx.x;
  const float* p = src + (size_t)b * 524288 + e;
  float m = -3e38f;
  for (int s = 0; s < 512; s += 8) {
    float v[8];
#pragma unroll
    for (int i = 0; i < 8; ++i) v[i] = __builtin_nontemporal_load(p + (size_t)(s + i) * 1024);
#pragma unroll
    for (int i = 0; i < 8; ++i) {
      m = fmaxf(m, v[i]);
      if (WRITE_B16) srcb[(size_t)b * 524288 + (size_t)(s + i) * 1024 + e] = f2b(v[i]);
    }
  }
  pooledb[b * 1024 + e] = f2b(m);
}

// Wcat rows permuted n' = j*4+g (g: 0=i,1=f,2=g,3=o); cols = [att|h|a|ty].
__global__ __launch_bounds__(256) void conv_wcat(const float* __restrict__ wih,
                                                 const float* __restrict__ whh,
                                                 unsigned short* __restrict__ wcat) {
  int idx = blockIdx.x * 256 + threadIdx.x;  // 4096*2304
  int np = idx / 2304;
  int k = idx - np * 2304;
  int j = np >> 2, g = np & 3;
  int n = g * 1024 + j;
  float v;
  if (k < 1024) v = wih[n * 1280 + 128 + k];
  else if (k < 2048) v = whh[n * 1024 + (k - 1024)];
  else if (k < 2176) v = wih[n * 1280 + (k - 2048)];
  else v = wih[n * 1280 + 1152 + (k - 2176)];
  wcat[idx] = f2b(v);
}

__global__ __launch_bounds__(256) void conv_bsum(const float* __restrict__ bih,
                                                 const float* __restrict__ bhh,
                                                 float* __restrict__ bsum) {
  int idx = blockIdx.x * 256 + threadIdx.x;  // 4096
  int j = idx >> 2, g = idx & 3;
  int n = g * 1024 + j;
  bsum[idx] = bih[n] + bhh[n];
}

__global__ __launch_bounds__(256) void conv_wattT(const float* __restrict__ watt,
                                                  unsigned short* __restrict__ wt) {
  int idx = blockIdx.x * 256 + threadIdx.x;  // 1024*1024
  int e = idx >> 10, h = idx & 1023;
  wt[idx] = f2b(watt[h * 1024 + e]);
}

__global__ __launch_bounds__(256) void conv_f2b(const float* __restrict__ s,
                                                unsigned short* __restrict__ d, int n) {
  int idx = blockIdx.x * 256 + threadIdx.x;
  if (idx < n) d[idx] = f2b(s[idx]);
}

__global__ __launch_bounds__(256) void conv_wqaT(const float* __restrict__ wqa,
                                                 float* __restrict__ wt) {
  int idx = blockIdx.x * 256 + threadIdx.x;  // 131072
  int k = idx >> 7, j = idx & 127;
  wt[idx] = wqa[j * 1024 + k];
}

__global__ __launch_bounds__(256) void conv_xaty(const int* __restrict__ action,
                                                 const int* __restrict__ type_ids,
                                                 const float* __restrict__ prod_emb,
                                                 const float* __restrict__ type_emb,
                                                 unsigned short* __restrict__ xaty) {
  int idx = blockIdx.x * 256 + threadIdx.x;  // 48*256*256
  int t = idx >> 16;
  int b = (idx >> 8) & 255;
  int kk = idx & 255;
  float v = 0.f;
  if (t > 0) {
    if (kk < 128) v = prod_emb[action[t * 256 + b] * 128 + kk];
    else v = type_emb[type_ids[t * 256 + b] * 128 + (kk - 128)];
  }
  xaty[idx] = f2b(v);
}

__global__ __launch_bounds__(256) void init0(unsigned short* __restrict__ xs0,
                                             float* __restrict__ c,
                                             unsigned* __restrict__ cnt) {
  int idx = blockIdx.x * 256 + threadIdx.x;  // 262144
  if (idx == 0) *cnt = 0u;
  int b = idx >> 10, e = idx & 1023;
  xs0[(size_t)b * 2048 + e] = 0;
  c[idx] = 0.f;
}

// ---------------- GEMM 64x64 (prep h0 only) ---------------------------------
template <int EPI, int K>
__global__ __launch_bounds__(256) void gemm_bt(const unsigned short* __restrict__ A, int lda,
                                               const unsigned short* __restrict__ B, int ldb,
                                               float* __restrict__ C, int ldc,
                                               const float* __restrict__ bias,
                                               unsigned short* __restrict__ aux, int aux_ld,
                                               int aux_off) {
  int lane = threadIdx.x & 63;
  int wid = threadIdx.x >> 6;
  int mw = blockIdx.y * 64 + (wid >> 1) * 32;
  int nw = blockIdx.x * 64 + (wid & 1) * 32;
  int lr = lane & 15;
  int kg = lane >> 4;
  const unsigned short* a0p = A + (size_t)(mw + lr) * lda + kg * 8;
  const unsigned short* a1p = a0p + (size_t)16 * lda;
  const unsigned short* b0p = B + (size_t)(nw + lr) * ldb + kg * 8;
  const unsigned short* b1p = b0p + (size_t)16 * ldb;
  f32x4 acc00 = {0.f, 0.f, 0.f, 0.f};
  f32x4 acc01 = acc00, acc10 = acc00, acc11 = acc00;
#pragma unroll 4
  for (int k = 0; k < K; k += 32) {
    s16x8 a0 = *(const s16x8*)(a0p + k);
    s16x8 a1 = *(const s16x8*)(a1p + k);
    s16x8 b0 = *(const s16x8*)(b0p + k);
    s16x8 b1 = *(const s16x8*)(b1p + k);
    acc00 = __builtin_amdgcn_mfma_f32_16x16x32_bf16(a0, b0, acc00, 0, 0, 0);
    acc01 = __builtin_amdgcn_mfma_f32_16x16x32_bf16(a0, b1, acc01, 0, 0, 0);
    acc10 = __builtin_amdgcn_mfma_f32_16x16x32_bf16(a1, b0, acc10, 0, 0, 0);
    acc11 = __builtin_amdgcn_mfma_f32_16x16x32_bf16(a1, b1, acc11, 0, 0, 0);
  }
  int r0 = mw + kg * 4;
  int c0 = nw + lr;
#pragma unroll
  for (int fi = 0; fi < 2; ++fi) {
#pragma unroll
    for (int fj = 0; fj < 2; ++fj) {
      f32x4 acc = (fi == 0) ? (fj == 0 ? acc00 : acc01) : (fj == 0 ? acc10 : acc11);
      int rr = r0 + fi * 16;
      int cc = c0 + fj * 16;
#pragma unroll
      for (int r = 0; r < 4; ++r) {
        float v = acc[r];
        if constexpr (EPI == 2) v = tanhf(v + bias[cc]);
        if constexpr (EPI == 1) v = tanhf(v);
        if constexpr (EPI != 0) aux[(size_t)(rr + r) * aux_ld + aux_off + cc] = f2b(v);
        if constexpr (EPI != 2) C[(size_t)(rr + r) * ldc + cc] = v;
      }
    }
  }
}

// ---------------- THE persistent kernel: all 48 steps ------------------------
template <int BF16P>
__global__ __launch_bounds__(1024) void decode_all(
    const unsigned short* __restrict__ srcb, const float* __restrict__ srcf,
    const unsigned short* __restrict__ xaty_all, const unsigned short* __restrict__ wcat,
    const float* __restrict__ bsum, float* __restrict__ cbuf,
    unsigned short* __restrict__ xs0, unsigned short* __restrict__ xs1,
    unsigned short* __restrict__ a2, float* __restrict__ qbuf,
    const unsigned short* __restrict__ wattT, const unsigned short* __restrict__ wav,
    float* __restrict__ attf, const float* __restrict__ wqaT,
    const float* __restrict__ b_qa, const float* __restrict__ prod_emb,
    const float* __restrict__ prod_bias, float* __restrict__ out,
    unsigned* __restrict__ cnt) {
  union SMem {
    float ld[64][68];  // phase A gate tile
    struct {
      unsigned short lctx[16][1024];
      float lm[16], ldn[16], lsc[16], sDinv;
    } c;  // phase C
    struct {
      float s_att[1024], s_part[128][9], s_q2[128], s_log[100], s_red[2];
    } e;  // phase E
  };
  __shared__ SMem sm;
  const int tid = threadIdx.x;
  const int lane = tid & 63;
  const int wv = tid >> 6;
  const int lr = lane & 15;
  const int kg = lane >> 4;
  const int blk = blockIdx.x;
  unsigned bt = 0;

  for (int t = 0; t < 48; ++t) {
    const unsigned short* xin = (t & 1) ? xs1 : xs0;
    unsigned short* xout = (t & 1) ? xs0 : xs1;
    const unsigned short* xaty = xaty_all + (size_t)t * 65536;

    // ---- phase A: gates GEMM (64x64 tile/block, 16 waves 16x16) + LSTM ----
    {
      int bx = blk & 63, by = blk >> 6;
      int wr = wv >> 2, wc = wv & 3;
      int mw = by * 64 + wr * 16;
      int nw = bx * 64 + wc * 16;
      const unsigned short* ap = xin + (size_t)(mw + lr) * 2048 + kg * 8;
      const unsigned short* bp = wcat + (size_t)(nw + lr) * 2304 + kg * 8;
      f32x4 acc = {0.f, 0.f, 0.f, 0.f};
#pragma unroll 4
      for (int k = 0; k < 2048; k += 32) {
        s16x8 a = *(const s16x8*)(ap + k);
        s16x8 b = *(const s16x8*)(bp + k);
        acc = __builtin_amdgcn_mfma_f32_16x16x32_bf16(a, b, acc, 0, 0, 0);
      }
      const unsigned short* cp = xaty + (size_t)(mw + lr) * 256 + kg * 8;
#pragma unroll
      for (int k = 0; k < 256; k += 32) {
        s16x8 a = *(const s16x8*)(cp + k);
        s16x8 b = *(const s16x8*)(bp + 2048 + k);
        acc = __builtin_amdgcn_mfma_f32_16x16x32_bf16(a, b, acc, 0, 0, 0);
      }
#pragma unroll
      for (int r = 0; r < 4; ++r) sm.ld[wr * 16 + kg * 4 + r][wc * 16 + lr] = acc[r];
      __syncthreads();
      int r = tid >> 4, u = tid & 15;  // row in tile, j-unit in tile
      int b = by * 64 + r;
      int j = bx * 16 + u;
      float4 bs = *(const float4*)(bsum + (size_t)j * 4);
      float vi = sm.ld[r][u * 4 + 0] + bs.x;
      float vf = sm.ld[r][u * 4 + 1] + bs.y;
      float vg = sm.ld[r][u * 4 + 2] + bs.z;
      float vo = sm.ld[r][u * 4 + 3] + bs.w;
      float co = cbuf[(size_t)b * 1024 + j];
      float ct = sigm(vf) * co + sigm(vi) * tanhf(vg);
      float ht = sigm(vo) * tanhf(ct);
      cbuf[(size_t)b * 1024 + j] = ct;
      unsigned short hb = f2b(ht);
      xout[(size_t)b * 2048 + 1024 + j] = hb;
      a2[(size_t)b * 2048 + j] = hb;
    }
    bt += 256; gbar(cnt, bt);

    // ---- phase B: q = h @ W_att  (16x64 tile/block, waves 0-3) ----
    if (wv < 4) {
      int bm = blk & 15, bn = blk >> 4;
      int row0 = bm * 16, col0 = bn * 64 + wv * 16;
      const unsigned short* ap = a2 + (size_t)(row0 + lr) * 2048 + kg * 8;
      const unsigned short* bp = wattT + (size_t)(col0 + lr) * 1024 + kg * 8;
      f32x4 acc = {0.f, 0.f, 0.f, 0.f};
#pragma unroll 8
      for (int k = 0; k < 1024; k += 32) {
        s16x8 a = *(const s16x8*)(ap + k);
        s16x8 b = *(const s16x8*)(bp + k);
        acc = __builtin_amdgcn_mfma_f32_16x16x32_bf16(a, b, acc, 0, 0, 0);
      }
#pragma unroll
      for (int r = 0; r < 4; ++r)
        qbuf[(size_t)(row0 + kg * 4 + r) * 1024 + col0 + lr] = acc[r];
    }
    bt += 256; gbar(cnt, bt);

    // ---- phase C: flash attention (block = one batch row) ----
    {
      int b = blk;
      float qr[16];
      {
        const float4* qp = (const float4*)(qbuf + (size_t)b * 1024 + lane * 16);
#pragma unroll
        for (int i = 0; i < 4; ++i) {
          float4 tq = qp[i];
          qr[4 * i] = tq.x; qr[4 * i + 1] = tq.y; qr[4 * i + 2] = tq.z; qr[4 * i + 3] = tq.w;
        }
      }
      float m = -3e38f, d = 0.f;
      float ctx[16];
#pragma unroll
      for (int i = 0; i < 16; ++i) ctx[i] = 0.f;
      int s0 = wv * 32;

      if (BF16P) {
        const unsigned short* rb = srcb + (size_t)b * 524288 + lane * 16;
        s16x8 u0 = __builtin_nontemporal_load((const s16x8*)(rb + (size_t)s0 * 1024));
        s16x8 u1 = __builtin_nontemporal_load((const s16x8*)(rb + (size_t)s0 * 1024 + 8));
        for (int s = 0; s < 32; ++s) {
          int rn = s0 + s + 1;
          rn = rn > 511 ? 511 : rn;
          s16x8 n0 = __builtin_nontemporal_load((const s16x8*)(rb + (size_t)rn * 1024));
          s16x8 n1 = __builtin_nontemporal_load((const s16x8*)(rb + (size_t)rn * 1024 + 8));
          float v[16];
#pragma unroll
          for (int i = 0; i < 8; ++i) {
            v[i] = b2f((unsigned short)u0[i]);
            v[8 + i] = b2f((unsigned short)u1[i]);
          }
          float sc = 0.f;
#pragma unroll
          for (int i = 0; i < 16; ++i) sc += v[i] * qr[i];
#pragma unroll
          for (int off = 1; off < 64; off <<= 1) sc += __shfl_xor(sc, off);
          float mn = fmaxf(m, sc);
          float scale = __expf(m - mn);
          float wgt = __expf(sc - mn);
          d = d * scale + wgt;
#pragma unroll
          for (int i = 0; i < 16; ++i) ctx[i] = ctx[i] * scale + wgt * v[i];
          m = mn;
          u0 = n0; u1 = n1;
        }
      } else {
        const float* rb = srcf + (size_t)b * 524288 + lane * 16;
        for (int s = 0; s < 32; ++s) {
          int rr = s0 + s;
          float v[16];
#pragma unroll
          for (int i = 0; i < 4; ++i) {
            f32x4 tq = __builtin_nontemporal_load((const f32x4*)(rb + (size_t)rr * 1024 + 4 * i));
            v[4 * i] = tq[0]; v[4 * i + 1] = tq[1]; v[4 * i + 2] = tq[2]; v[4 * i + 3] = tq[3];
          }
          float sc = 0.f;
#pragma unroll
          for (int i = 0; i < 16; ++i) sc += v[i] * qr[i];
#pragma unroll
          for (int off = 1; off < 64; off <<= 1) sc += __shfl_xor(sc, off);
          float mn = fmaxf(m, sc);
          float scale = __expf(m - mn);
          float wgt = __expf(sc - mn);
          d = d * scale + wgt;
#pragma unroll
          for (int i = 0; i < 16; ++i) ctx[i] = ctx[i] * scale + wgt * v[i];
          m = mn;
        }
      }

#pragma unroll
      for (int i = 0; i < 16; ++i) sm.c.lctx[wv][lane * 16 + i] = f2b(ctx[i]);
      if (lane == 0) { sm.c.lm[wv] = m; sm.c.ldn[wv] = d; }
      __syncthreads();
      if (tid == 0) {
        float M = sm.c.lm[0];
        for (int w2 = 1; w2 < 16; ++w2) M = fmaxf(M, sm.c.lm[w2]);
        float D = 0.f;
        for (int w2 = 0; w2 < 16; ++w2) {
          float sc = __expf(sm.c.lm[w2] - M);
          sm.c.lsc[w2] = sc;
          D += sc * sm.c.ldn[w2];
        }
        sm.c.sDinv = 1.f / D;
      }
      __syncthreads();
      float acc2 = 0.f;
#pragma unroll
      for (int w2 = 0; w2 < 16; ++w2) acc2 += sm.c.lsc[w2] * b2f(sm.c.lctx[w2][tid]);
      a2[(size_t)b * 2048 + 1024 + tid] = f2b(acc2 * sm.c.sDinv);
    }
    bt += 256; gbar(cnt, bt);

    // ---- phase D: att = tanh([h|ctx] @ W_av^T)  (16x64 tile, waves 0-3) ----
    if (wv < 4) {
      int bm = blk & 15, bn = blk >> 4;
      int row0 = bm * 16, col0 = bn * 64 + wv * 16;
      const unsigned short* ap = a2 + (size_t)(row0 + lr) * 2048 + kg * 8;
      const unsigned short* bp = wav + (size_t)(col0 + lr) * 2048 + kg * 8;
      f32x4 acc = {0.f, 0.f, 0.f, 0.f};
#pragma unroll 8
      for (int k = 0; k < 2048; k += 32) {
        s16x8 a = *(const s16x8*)(ap + k);
        s16x8 b = *(const s16x8*)(bp + k);
        acc = __builtin_amdgcn_mfma_f32_16x16x32_bf16(a, b, acc, 0, 0, 0);
      }
#pragma unroll
      for (int r = 0; r < 4; ++r) {
        float v = tanhf(acc[r]);
        int row = row0 + kg * 4 + r, col = col0 + lr;
        attf[(size_t)row * 1024 + col] = v;
        xout[(size_t)row * 2048 + col] = f2b(v);  // att slice (offset 0)
      }
    }
    bt += 256; gbar(cnt, bt);

    // ---- phase E: readout (block = one batch row) ----
    {
      int b = blk;
      sm.e.s_att[tid] = attf[(size_t)b * 1024 + tid];
      __syncthreads();
      int j = tid & 127, part = tid >> 7;
      float p = 0.f;
      for (int k = 0; k < 128; ++k)
        p += sm.e.s_att[part * 128 + k] * wqaT[(size_t)(part * 128 + k) * 128 + j];
      sm.e.s_part[j][part] = p;
      __syncthreads();
      if (tid < 128) {
        float acc = b_qa[tid];
#pragma unroll
        for (int q = 0; q < 8; ++q) acc += sm.e.s_part[tid][q];
        sm.e.s_q2[tid] = tanhf(acc);
      }
      __syncthreads();
      if (tid < 97) {
        float a = prod_bias[tid];
        const float* pe = prod_emb + tid * 128;
        float aa = 0.f;
        for (int k = 0; k < 128; ++k) aa += sm.e.s_q2[k] * pe[k];
        sm.e.s_log[tid] = a + aa;
      }
      __syncthreads();
      if (tid == 0) {
        float M = sm.e.s_log[0];
        for (int k = 1; k < 97; ++k) M = fmaxf(M, sm.e.s_log[k]);
        float D = 0.f;
        for (int k = 0; k < 97; ++k) D += __expf(sm.e.s_log[k] - M);
        sm.e.s_red[0] = M;
        sm.e.s_red[1] = D;
      }
      __syncthreads();
      if (tid < 97)
        out[((size_t)t * 256 + b) * 97 + tid] =
            __expf(sm.e.s_log[tid] - sm.e.s_red[0]) / sm.e.s_red[1];
      __syncthreads();  // protect LDS union before next step's phase A
    }
  }
}

// ---------------------------------------------------------------------------

extern "C" void kernel_launch(void* const* d_in, const int* in_sizes, int n_in,
                              void* d_out, int out_size, void* d_ws, size_t ws_size,
                              hipStream_t stream) {
  const float* src = (const float*)d_in[0];
  const int* action = (const int*)d_in[1];
  const int* type_ids = (const int*)d_in[2];
  const float* W_ih = (const float*)d_in[3];
  const float* b_ih = (const float*)d_in[4];
  const float* W_hh = (const float*)d_in[5];
  const float* b_hh = (const float*)d_in[6];
  const float* W_att = (const float*)d_in[7];
  const float* W_av = (const float*)d_in[8];
  const float* W_qa = (const float*)d_in[9];
  const float* b_qa = (const float*)d_in[10];
  const float* prod_emb = (const float*)d_in[11];
  const float* prod_bias = (const float*)d_in[12];
  const float* type_emb = (const float*)d_in[13];
  const float* W_init = (const float*)d_in[14];
  const float* b_init = (const float*)d_in[15];
  float* out = (float*)d_out;

  const size_t NEED_SMALL = 40911104ull;
  const size_t NEED_BIG = 309346560ull;
  bool big = ws_size >= NEED_BIG;
  if (!big && ws_size < NEED_SMALL) return;

  char* w = (char*)d_ws;
  size_t o = 0;
  unsigned short* wcat = (unsigned short*)(w + o); o += 18874368ull;
  unsigned short* wattT = (unsigned short*)(w + o); o += 2097152ull;
  unsigned short* wav = (unsigned short*)(w + o); o += 4194304ull;
  float* wqaT = (float*)(w + o); o += 524288ull;
  unsigned short* xaty = (unsigned short*)(w + o); o += 6291456ull;
  unsigned short* xstate0 = (unsigned short*)(w + o); o += 1048576ull;
  unsigned short* xstate1 = (unsigned short*)(w + o); o += 1048576ull;
  unsigned short* a2 = (unsigned short*)(w + o); o += 1048576ull;
  float* cbuf = (float*)(w + o); o += 1048576ull;
  float* qbuf = (float*)(w + o); o += 1048576ull;
  float* attf = (float*)(w + o); o += 1048576ull;
  unsigned short* pooledb = (unsigned short*)(w + o); o += 524288ull;
  unsigned short* winitb = (unsigned short*)(w + o); o += 2097152ull;
  float* bsum = (float*)(w + o); o += 16384ull;
  unsigned* cnt = (unsigned*)(w + o); o += 256ull;
  unsigned short* srcb = nullptr;
  if (big) { srcb = (unsigned short*)(w + o); o += 268435456ull; }

  // ---- prep ----
  if (big) pool_convert<1><<<1024, 256, 0, stream>>>(src, srcb, pooledb);
  else     pool_convert<0><<<1024, 256, 0, stream>>>(src, nullptr, pooledb);
  conv_wcat<<<36864, 256, 0, stream>>>(W_ih, W_hh, wcat);
  conv_bsum<<<16, 256, 0, stream>>>(b_ih, b_hh, bsum);
  conv_wattT<<<4096, 256, 0, stream>>>(W_att, wattT);
  conv_f2b<<<8192, 256, 0, stream>>>(W_av, wav, 2097152);
  conv_f2b<<<4096, 256, 0, stream>>>(W_init, winitb, 1048576);
  conv_wqaT<<<512, 256, 0, stream>>>(W_qa, wqaT);
  conv_xaty<<<12288, 256, 0, stream>>>(action, type_ids, prod_emb, type_emb, xaty);
  init0<<<1024, 256, 0, stream>>>(xstate0, cbuf, cnt);
  gemm_bt<2, 1024><<<dim3(16, 4), 256, 0, stream>>>(pooledb, 1024, winitb, 1024,
                                                    nullptr, 0, b_init, xstate0, 2048, 1024);

  // ---- all 48 steps in one persistent kernel ----
  if (big)
    decode_all<1><<<256, 1024, 0, stream>>>(srcb, nullptr, xaty, wcat, bsum, cbuf,
                                            xstate0, xstate1, a2, qbuf, wattT, wav, attf,
                                            wqaT, b_qa, prod_emb, prod_bias, out, cnt);
  else
    decode_all<0><<<256, 1024, 0, stream>>>(nullptr, src, xaty, wcat, bsum, cbuf,
                                            xstate0, xstate1, a2, qbuf, wattT, wav, attf,
                                            wqaT, b_qa, prod_emb, prod_bias, out, cnt);
}

// Round 6
// 11423.329 us; speedup vs baseline: 1.1213x; 1.1213x over previous
//
#include <hip/hip_runtime.h>

// ---------------------------------------------------------------------------
// SQLDecoder: 48-step recurrent decoder. ONE kernel per step (60 graph nodes),
// 3 contention-free flag barriers inside each step kernel.
//   * scores = src @ (h @ W_att); single-pass online-softmax attn (K==V==src)
//   * src cached bf16, non-temporal reads; bf16 MFMA GEMMs; fp32 cell/readout
//   * phases: A gates(4 waves)+LSTM (+readout(t-1) on wave 4) | B q | C flash
//             (8 waves x 64 rows, prefetch-2) | D att  -- barriers between
// B=256 S=512 E=H=AV=1024 T=48 NP=97 K_state=2048 K_cat=2304
// ---------------------------------------------------------------------------

typedef short s16x8 __attribute__((ext_vector_type(8)));
typedef float f32x4 __attribute__((ext_vector_type(4)));

__device__ __forceinline__ unsigned short f2b(float x) {
  unsigned int u = __float_as_uint(x);
  return (unsigned short)((u + 0x7fffu + ((u >> 16) & 1u)) >> 16);  // RNE
}
__device__ __forceinline__ float b2f(unsigned short h) {
  return __uint_as_float(((unsigned int)h) << 16);
}
__device__ __forceinline__ float sigm(float x) { return 1.f / (1.f + __expf(-x)); }

// contention-free device barrier: per-block padded flag + all-scan.
// Fence pattern (threadfence + AGENT atomics) validated correct in round 5.
__device__ __forceinline__ void sbar(unsigned* flags, unsigned epoch) {
  __syncthreads();
  if (threadIdx.x == 0) {
    __threadfence();  // release: wbl2 drains this XCD's dirty lines
    __hip_atomic_store(flags + (size_t)blockIdx.x * 32, epoch, __ATOMIC_RELEASE,
                       __HIP_MEMORY_SCOPE_AGENT);
  }
  if (threadIdx.x < 64) {
    for (;;) {
      unsigned ok = 1;
#pragma unroll
      for (int i = 0; i < 4; ++i) {
        unsigned v = __hip_atomic_load(flags + (size_t)(threadIdx.x + 64 * i) * 32,
                                       __ATOMIC_ACQUIRE, __HIP_MEMORY_SCOPE_AGENT);
        ok &= (v >= epoch);
      }
      if (__all(ok)) break;
      __builtin_amdgcn_s_sleep(4);
    }
  }
  __syncthreads();
  if (threadIdx.x == 0) __threadfence();  // acquire: invalidate stale L1/L2
  __syncthreads();
}

// ---------------- prep kernels ----------------------------------------------

template <int WRITE_B16>
__global__ __launch_bounds__(256) void pool_convert(const float* __restrict__ src,
                                                    unsigned short* __restrict__ srcb,
                                                    unsigned short* __restrict__ pooledb) {
  int b = blockIdx.x >> 2;
  int e = (blockIdx.x & 3) * 256 + threadIdx.x;
  const float* p = src + (size_t)b * 524288 + e;
  float m = -3e38f;
  for (int s = 0; s < 512; s += 8) {
    float v[8];
#pragma unroll
    for (int i = 0; i < 8; ++i) v[i] = __builtin_nontemporal_load(p + (size_t)(s + i) * 1024);
#pragma unroll
    for (int i = 0; i < 8; ++i) {
      m = fmaxf(m, v[i]);
      if (WRITE_B16) srcb[(size_t)b * 524288 + (size_t)(s + i) * 1024 + e] = f2b(v[i]);
    }
  }
  pooledb[b * 1024 + e] = f2b(m);
}

// Wcat rows permuted n' = j*4+g (g: 0=i,1=f,2=g,3=o); cols = [att|h|a|ty].
__global__ __launch_bounds__(256) void conv_wcat(const float* __restrict__ wih,
                                                 const float* __restrict__ whh,
                                                 unsigned short* __restrict__ wcat) {
  int idx = blockIdx.x * 256 + threadIdx.x;  // 4096*2304
  int np = idx / 2304;
  int k = idx - np * 2304;
  int j = np >> 2, g = np & 3;
  int n = g * 1024 + j;
  float v;
  if (k < 1024) v = wih[n * 1280 + 128 + k];
  else if (k < 2048) v = whh[n * 1024 + (k - 1024)];
  else if (k < 2176) v = wih[n * 1280 + (k - 2048)];
  else v = wih[n * 1280 + 1152 + (k - 2176)];
  wcat[idx] = f2b(v);
}

__global__ __launch_bounds__(256) void conv_bsum(const float* __restrict__ bih,
                                                 const float* __restrict__ bhh,
                                                 float* __restrict__ bsum) {
  int idx = blockIdx.x * 256 + threadIdx.x;  // 4096
  int j = idx >> 2, g = idx & 3;
  int n = g * 1024 + j;
  bsum[idx] = bih[n] + bhh[n];
}

__global__ __launch_bounds__(256) void conv_wattT(const float* __restrict__ watt,
                                                  unsigned short* __restrict__ wt) {
  int idx = blockIdx.x * 256 + threadIdx.x;  // 1024*1024
  int e = idx >> 10, h = idx & 1023;
  wt[idx] = f2b(watt[h * 1024 + e]);
}

__global__ __launch_bounds__(256) void conv_f2b(const float* __restrict__ s,
                                                unsigned short* __restrict__ d, int n) {
  int idx = blockIdx.x * 256 + threadIdx.x;
  if (idx < n) d[idx] = f2b(s[idx]);
}

__global__ __launch_bounds__(256) void conv_wqaT(const float* __restrict__ wqa,
                                                 float* __restrict__ wt) {
  int idx = blockIdx.x * 256 + threadIdx.x;  // 131072
  int k = idx >> 7, j = idx & 127;
  wt[idx] = wqa[j * 1024 + k];
}

__global__ __launch_bounds__(256) void conv_xaty(const int* __restrict__ action,
                                                 const int* __restrict__ type_ids,
                                                 const float* __restrict__ prod_emb,
                                                 const float* __restrict__ type_emb,
                                                 unsigned short* __restrict__ xaty) {
  int idx = blockIdx.x * 256 + threadIdx.x;  // 48*256*256
  int t = idx >> 16;
  int b = (idx >> 8) & 255;
  int kk = idx & 255;
  float v = 0.f;
  if (t > 0) {
    if (kk < 128) v = prod_emb[action[t * 256 + b] * 128 + kk];
    else v = type_emb[type_ids[t * 256 + b] * 128 + (kk - 128)];
  }
  xaty[idx] = f2b(v);
}

__global__ __launch_bounds__(256) void init0(unsigned short* __restrict__ xs0,
                                             float* __restrict__ c,
                                             unsigned* __restrict__ flags) {
  int idx = blockIdx.x * 256 + threadIdx.x;  // 262144
  if (idx < 8192) flags[idx] = 0u;
  int b = idx >> 10, e = idx & 1023;
  xs0[(size_t)b * 2048 + e] = 0;
  c[idx] = 0.f;
}

// ---------------- GEMM 64x64 (h0 prep only) ---------------------------------
template <int EPI, int K>
__global__ __launch_bounds__(256) void gemm_bt(const unsigned short* __restrict__ A, int lda,
                                               const unsigned short* __restrict__ B, int ldb,
                                               float* __restrict__ C, int ldc,
                                               const float* __restrict__ bias,
                                               unsigned short* __restrict__ aux, int aux_ld,
                                               int aux_off) {
  int lane = threadIdx.x & 63;
  int wid = threadIdx.x >> 6;
  int mw = blockIdx.y * 64 + (wid >> 1) * 32;
  int nw = blockIdx.x * 64 + (wid & 1) * 32;
  int lr = lane & 15;
  int kg = lane >> 4;
  const unsigned short* a0p = A + (size_t)(mw + lr) * lda + kg * 8;
  const unsigned short* a1p = a0p + (size_t)16 * lda;
  const unsigned short* b0p = B + (size_t)(nw + lr) * ldb + kg * 8;
  const unsigned short* b1p = b0p + (size_t)16 * ldb;
  f32x4 acc00 = {0.f, 0.f, 0.f, 0.f};
  f32x4 acc01 = acc00, acc10 = acc00, acc11 = acc00;
#pragma unroll 4
  for (int k = 0; k < K; k += 32) {
    s16x8 a0 = *(const s16x8*)(a0p + k);
    s16x8 a1 = *(const s16x8*)(a1p + k);
    s16x8 b0 = *(const s16x8*)(b0p + k);
    s16x8 b1 = *(const s16x8*)(b1p + k);
    acc00 = __builtin_amdgcn_mfma_f32_16x16x32_bf16(a0, b0, acc00, 0, 0, 0);
    acc01 = __builtin_amdgcn_mfma_f32_16x16x32_bf16(a0, b1, acc01, 0, 0, 0);
    acc10 = __builtin_amdgcn_mfma_f32_16x16x32_bf16(a1, b0, acc10, 0, 0, 0);
    acc11 = __builtin_amdgcn_mfma_f32_16x16x32_bf16(a1, b1, acc11, 0, 0, 0);
  }
  int r0 = mw + kg * 4;
  int c0 = nw + lr;
#pragma unroll
  for (int fi = 0; fi < 2; ++fi) {
#pragma unroll
    for (int fj = 0; fj < 2; ++fj) {
      f32x4 acc = (fi == 0) ? (fj == 0 ? acc00 : acc01) : (fj == 0 ? acc10 : acc11);
      int rr = r0 + fi * 16;
      int cc = c0 + fj * 16;
#pragma unroll
      for (int r = 0; r < 4; ++r) {
        float v = acc[r];
        if constexpr (EPI == 2) v = tanhf(v + bias[cc]);
        if constexpr (EPI == 1) v = tanhf(v);
        if constexpr (EPI != 0) aux[(size_t)(rr + r) * aux_ld + aux_off + cc] = f2b(v);
        if constexpr (EPI != 2) C[(size_t)(rr + r) * ldc + cc] = v;
      }
    }
  }
}

// ---------------- ONE STEP: A gates+LSTM | B q | C flash | D att ------------
template <int BF16P>
__global__ __launch_bounds__(512) void step_kernel(
    const unsigned short* __restrict__ srcb, const float* __restrict__ srcf,
    const unsigned short* __restrict__ xin, unsigned short* __restrict__ xout,
    const unsigned short* __restrict__ xaty, const unsigned short* __restrict__ wcat,
    const float* __restrict__ bsum, float* __restrict__ cbuf,
    unsigned short* __restrict__ a2, float* __restrict__ qbuf,
    const unsigned short* __restrict__ wattT, const unsigned short* __restrict__ wav,
    float* __restrict__ attf, const float* __restrict__ wqaT,
    const float* __restrict__ b_qa, const float* __restrict__ prod_emb,
    const float* __restrict__ prod_bias, float* __restrict__ out,
    unsigned* __restrict__ flags, int t) {
  union SMem {
    struct { float ld[64][68]; float ro[132]; } a;
    struct { unsigned short lctx[8][1024]; float lm[8], ldn[8], lsc[8], sDinv; } c;
  };
  __shared__ SMem sm;
  const int tid = threadIdx.x;
  const int lane = tid & 63;
  const int wv = tid >> 6;  // 0..7
  const int lr = lane & 15;
  const int kg = lane >> 4;
  const int blk = blockIdx.x;
  const unsigned ep = 3u * (unsigned)t;

  // ======== phase A: gates GEMM (waves 0-3) + readout(t-1) (wave 4) ========
  const int bx = blk & 63, by = blk >> 6;
  if (wv < 4) {
    int mwl = (wv >> 1) * 32;
    int nwl = (wv & 1) * 32;
    int mw = by * 64 + mwl;
    int nw = bx * 64 + nwl;
    const unsigned short* a0p = xin + (size_t)(mw + lr) * 2048 + kg * 8;
    const unsigned short* a1p = a0p + (size_t)16 * 2048;
    const unsigned short* b0p = wcat + (size_t)(nw + lr) * 2304 + kg * 8;
    const unsigned short* b1p = b0p + (size_t)16 * 2304;
    f32x4 acc00 = {0.f, 0.f, 0.f, 0.f};
    f32x4 acc01 = acc00, acc10 = acc00, acc11 = acc00;
#pragma unroll 8
    for (int k = 0; k < 2048; k += 32) {
      s16x8 a0 = *(const s16x8*)(a0p + k);
      s16x8 a1 = *(const s16x8*)(a1p + k);
      s16x8 b0 = *(const s16x8*)(b0p + k);
      s16x8 b1 = *(const s16x8*)(b1p + k);
      acc00 = __builtin_amdgcn_mfma_f32_16x16x32_bf16(a0, b0, acc00, 0, 0, 0);
      acc01 = __builtin_amdgcn_mfma_f32_16x16x32_bf16(a0, b1, acc01, 0, 0, 0);
      acc10 = __builtin_amdgcn_mfma_f32_16x16x32_bf16(a1, b0, acc10, 0, 0, 0);
      acc11 = __builtin_amdgcn_mfma_f32_16x16x32_bf16(a1, b1, acc11, 0, 0, 0);
    }
    const unsigned short* c0p = xaty + (size_t)(mw + lr) * 256 + kg * 8;
    const unsigned short* c1p = c0p + (size_t)16 * 256;
#pragma unroll
    for (int k = 0; k < 256; k += 32) {
      s16x8 a0 = *(const s16x8*)(c0p + k);
      s16x8 a1 = *(const s16x8*)(c1p + k);
      s16x8 b0 = *(const s16x8*)(b0p + 2048 + k);
      s16x8 b1 = *(const s16x8*)(b1p + 2048 + k);
      acc00 = __builtin_amdgcn_mfma_f32_16x16x32_bf16(a0, b0, acc00, 0, 0, 0);
      acc01 = __builtin_amdgcn_mfma_f32_16x16x32_bf16(a0, b1, acc01, 0, 0, 0);
      acc10 = __builtin_amdgcn_mfma_f32_16x16x32_bf16(a1, b0, acc10, 0, 0, 0);
      acc11 = __builtin_amdgcn_mfma_f32_16x16x32_bf16(a1, b1, acc11, 0, 0, 0);
    }
    int r0 = mwl + kg * 4;
    int c0 = nwl + lr;
#pragma unroll
    for (int fi = 0; fi < 2; ++fi)
#pragma unroll
      for (int fj = 0; fj < 2; ++fj) {
        f32x4 acc = (fi == 0) ? (fj == 0 ? acc00 : acc01) : (fj == 0 ? acc10 : acc11);
#pragma unroll
        for (int r = 0; r < 4; ++r) sm.a.ld[r0 + fi * 16 + r][c0 + fj * 16] = acc[r];
      }
  } else if (wv == 4 && t > 0) {
    // ---- readout for step t-1, batch = blk (wave-local; hidden under GEMM) ----
    int b = blk;
    const float* ap = attf + (size_t)b * 1024;
    float acc0 = b_qa[lane], acc1 = b_qa[lane + 64];
    for (int k = 0; k < 1024; k += 4) {
      float4 av = *(const float4*)(ap + k);
      const float* wq = wqaT + (size_t)k * 128 + lane;
      acc0 += av.x * wq[0];        acc1 += av.x * wq[64];
      acc0 += av.y * wq[128];      acc1 += av.y * wq[192];
      acc0 += av.z * wq[256];      acc1 += av.z * wq[320];
      acc0 += av.w * wq[384];      acc1 += av.w * wq[448];
    }
    sm.a.ro[lane] = tanhf(acc0);
    sm.a.ro[lane + 64] = tanhf(acc1);  // wave-local LDS: in-order, no barrier
    float l0, l1 = -3e38f;
    {
      const float* pe = prod_emb + lane * 128;
      float s = prod_bias[lane];
      for (int k = 0; k < 128; ++k) s += sm.a.ro[k] * pe[k];
      l0 = s;
    }
    if (lane < 33) {
      const float* pe = prod_emb + (lane + 64) * 128;
      float s = prod_bias[lane + 64];
      for (int k = 0; k < 128; ++k) s += sm.a.ro[k] * pe[k];
      l1 = s;
    }
    float mx = fmaxf(l0, l1);
#pragma unroll
    for (int off = 1; off < 64; off <<= 1) mx = fmaxf(mx, __shfl_xor(mx, off));
    float e0 = __expf(l0 - mx);
    float e1 = (lane < 33) ? __expf(l1 - mx) : 0.f;
    float sum = e0 + e1;
#pragma unroll
    for (int off = 1; off < 64; off <<= 1) sum += __shfl_xor(sum, off);
    float inv = 1.f / sum;
    float* op = out + ((size_t)(t - 1) * 256 + b) * 97;
    op[lane] = e0 * inv;
    if (lane < 33) op[lane + 64] = e1 * inv;
  }
  __syncthreads();
  {  // LSTM epilogue: 512 threads, each 2 j-units
    int row = tid >> 3;
    int ue = (tid & 7) * 2;
    int b = by * 64 + row;
    int jb = bx * 16 + ue;
    float2 cold = *(const float2*)(cbuf + (size_t)b * 1024 + jb);
    float cn[2];
    unsigned short hbv[2];
#pragma unroll
    for (int i = 0; i < 2; ++i) {
      int u = ue + i;
      float4 bs = *(const float4*)(bsum + (size_t)(bx * 16 + u) * 4);
      float vi = sm.a.ld[row][u * 4 + 0] + bs.x;
      float vf = sm.a.ld[row][u * 4 + 1] + bs.y;
      float vg = sm.a.ld[row][u * 4 + 2] + bs.z;
      float vo = sm.a.ld[row][u * 4 + 3] + bs.w;
      float co = i ? cold.y : cold.x;
      float ct = sigm(vf) * co + sigm(vi) * tanhf(vg);
      float ht = sigm(vo) * tanhf(ct);
      cn[i] = ct;
      hbv[i] = f2b(ht);
    }
    *(float2*)(cbuf + (size_t)b * 1024 + jb) = make_float2(cn[0], cn[1]);
    *(ushort2*)(xout + (size_t)b * 2048 + 1024 + jb) = make_ushort2(hbv[0], hbv[1]);
    *(ushort2*)(a2 + (size_t)b * 2048 + jb) = make_ushort2(hbv[0], hbv[1]);
  }
  sbar(flags, ep + 1);

  // ======== phase B: q = h @ W_att (waves 0-3, 32x32 tile per block) ========
  if (wv < 4) {
    int bxq = blk & 31, byq = blk >> 5;
    int mw = byq * 32 + (wv >> 1) * 16;
    int nw = bxq * 32 + (wv & 1) * 16;
    const unsigned short* ap = a2 + (size_t)(mw + lr) * 2048 + kg * 8;
    const unsigned short* bp = wattT + (size_t)(nw + lr) * 1024 + kg * 8;
    f32x4 acc = {0.f, 0.f, 0.f, 0.f};
#pragma unroll 8
    for (int k = 0; k < 1024; k += 32) {
      s16x8 a = *(const s16x8*)(ap + k);
      s16x8 b = *(const s16x8*)(bp + k);
      acc = __builtin_amdgcn_mfma_f32_16x16x32_bf16(a, b, acc, 0, 0, 0);
    }
#pragma unroll
    for (int r = 0; r < 4; ++r) qbuf[(size_t)(mw + kg * 4 + r) * 1024 + nw + lr] = acc[r];
  }
  sbar(flags, ep + 2);

  // ======== phase C: flash attention (8 waves x 64 rows, prefetch-2) ========
  {
    int b = blk;
    float qr[16];
    {
      const float4* qp = (const float4*)(qbuf + (size_t)b * 1024 + lane * 16);
#pragma unroll
      for (int i = 0; i < 4; ++i) {
        float4 tq = qp[i];
        qr[4 * i] = tq.x; qr[4 * i + 1] = tq.y; qr[4 * i + 2] = tq.z; qr[4 * i + 3] = tq.w;
      }
    }
    float m = -3e38f, d = 0.f;
    float ctx[16];
#pragma unroll
    for (int i = 0; i < 16; ++i) ctx[i] = 0.f;
    int s0 = wv * 64;

    if (BF16P) {
      const unsigned short* rb = srcb + (size_t)b * 524288 + lane * 16;
      s16x8 c0 = __builtin_nontemporal_load((const s16x8*)(rb + (size_t)s0 * 1024));
      s16x8 c1 = __builtin_nontemporal_load((const s16x8*)(rb + (size_t)s0 * 1024 + 8));
      s16x8 d0 = __builtin_nontemporal_load((const s16x8*)(rb + (size_t)(s0 + 1) * 1024));
      s16x8 d1 = __builtin_nontemporal_load((const s16x8*)(rb + (size_t)(s0 + 1) * 1024 + 8));
      for (int s = 0; s < 64; ++s) {
        int rn = s0 + s + 2;
        rn = rn > 511 ? 511 : rn;
        s16x8 e0 = __builtin_nontemporal_load((const s16x8*)(rb + (size_t)rn * 1024));
        s16x8 e1 = __builtin_nontemporal_load((const s16x8*)(rb + (size_t)rn * 1024 + 8));
        float v[16];
#pragma unroll
        for (int i = 0; i < 8; ++i) {
          v[i] = b2f((unsigned short)c0[i]);
          v[8 + i] = b2f((unsigned short)c1[i]);
        }
        float sc = 0.f;
#pragma unroll
        for (int i = 0; i < 16; ++i) sc += v[i] * qr[i];
#pragma unroll
        for (int off = 1; off < 64; off <<= 1) sc += __shfl_xor(sc, off);
        float mn = fmaxf(m, sc);
        float scale = __expf(m - mn);
        float wgt = __expf(sc - mn);
        d = d * scale + wgt;
#pragma unroll
        for (int i = 0; i < 16; ++i) ctx[i] = ctx[i] * scale + wgt * v[i];
        m = mn;
        c0 = d0; c1 = d1; d0 = e0; d1 = e1;
      }
    } else {
      const float* rb = srcf + (size_t)b * 524288 + lane * 16;
      for (int s = 0; s < 64; ++s) {
        int rr = s0 + s;
        float v[16];
#pragma unroll
        for (int i = 0; i < 4; ++i) {
          f32x4 tq = __builtin_nontemporal_load((const f32x4*)(rb + (size_t)rr * 1024 + 4 * i));
          v[4 * i] = tq[0]; v[4 * i + 1] = tq[1]; v[4 * i + 2] = tq[2]; v[4 * i + 3] = tq[3];
        }
        float sc = 0.f;
#pragma unroll
        for (int i = 0; i < 16; ++i) sc += v[i] * qr[i];
#pragma unroll
        for (int off = 1; off < 64; off <<= 1) sc += __shfl_xor(sc, off);
        float mn = fmaxf(m, sc);
        float scale = __expf(m - mn);
        float wgt = __expf(sc - mn);
        d = d * scale + wgt;
#pragma unroll
        for (int i = 0; i < 16; ++i) ctx[i] = ctx[i] * scale + wgt * v[i];
        m = mn;
      }
    }

#pragma unroll
    for (int i = 0; i < 16; ++i) sm.c.lctx[wv][lane * 16 + i] = f2b(ctx[i]);
    if (lane == 0) { sm.c.lm[wv] = m; sm.c.ldn[wv] = d; }
    __syncthreads();
    if (tid == 0) {
      float M = sm.c.lm[0];
      for (int w2 = 1; w2 < 8; ++w2) M = fmaxf(M, sm.c.lm[w2]);
      float D = 0.f;
      for (int w2 = 0; w2 < 8; ++w2) {
        float sc = __expf(sm.c.lm[w2] - M);
        sm.c.lsc[w2] = sc;
        D += sc * sm.c.ldn[w2];
      }
      sm.c.sDinv = 1.f / D;
    }
    __syncthreads();
#pragma unroll
    for (int half = 0; half < 2; ++half) {
      int e = tid + half * 512;
      float acc2 = 0.f;
#pragma unroll
      for (int w2 = 0; w2 < 8; ++w2) acc2 += sm.c.lsc[w2] * b2f(sm.c.lctx[w2][e]);
      a2[(size_t)b * 2048 + 1024 + e] = f2b(acc2 * sm.c.sDinv);
    }
  }
  sbar(flags, ep + 3);

  // ======== phase D: att = tanh([h|ctx] @ W_av^T) (waves 0-3) ========
  if (wv < 4) {
    int bxq = blk & 31, byq = blk >> 5;
    int mw = byq * 32 + (wv >> 1) * 16;
    int nw = bxq * 32 + (wv & 1) * 16;
    const unsigned short* ap = a2 + (size_t)(mw + lr) * 2048 + kg * 8;
    const unsigned short* bp = wav + (size_t)(nw + lr) * 2048 + kg * 8;
    f32x4 acc = {0.f, 0.f, 0.f, 0.f};
#pragma unroll 8
    for (int k = 0; k < 2048; k += 32) {
      s16x8 a = *(const s16x8*)(ap + k);
      s16x8 b = *(const s16x8*)(bp + k);
      acc = __builtin_amdgcn_mfma_f32_16x16x32_bf16(a, b, acc, 0, 0, 0);
    }
#pragma unroll
    for (int r = 0; r < 4; ++r) {
      float v = tanhf(acc[r]);
      int row = mw + kg * 4 + r, col = nw + lr;
      attf[(size_t)row * 1024 + col] = v;
      xout[(size_t)row * 2048 + col] = f2b(v);  // att slice (offset 0)
    }
  }
  // kernel end = device-wide sync before next step's node
}

// ---------------- standalone readout (final step) ----------------------------
__global__ __launch_bounds__(128) void readout(const float* __restrict__ att,
                                               const float* __restrict__ wqaT,
                                               const float* __restrict__ b_qa,
                                               const float* __restrict__ prod_emb,
                                               const float* __restrict__ prod_bias,
                                               float* __restrict__ out, int t) {
  __shared__ float s_att[1024], s_q2[128], s_log[97], s_red[2];
  int b = blockIdx.x;
  int tid = threadIdx.x;
  for (int i = tid; i < 1024; i += 128) s_att[i] = att[(size_t)b * 1024 + i];
  __syncthreads();
  float acc = b_qa[tid];
  for (int k = 0; k < 1024; ++k) acc += s_att[k] * wqaT[k * 128 + tid];
  s_q2[tid] = tanhf(acc);
  __syncthreads();
  if (tid < 97) {
    float a = prod_bias[tid];
    const float* pe = prod_emb + tid * 128;
    for (int k = 0; k < 128; ++k) a += s_q2[k] * pe[k];
    s_log[tid] = a;
  }
  __syncthreads();
  if (tid == 0) {
    float M = s_log[0];
    for (int k = 1; k < 97; ++k) M = fmaxf(M, s_log[k]);
    float D = 0.f;
    for (int k = 0; k < 97; ++k) D += __expf(s_log[k] - M);
    s_red[0] = M;
    s_red[1] = D;
  }
  __syncthreads();
  if (tid < 97)
    out[((size_t)t * 256 + b) * 97 + tid] = __expf(s_log[tid] - s_red[0]) / s_red[1];
}

// ---------------------------------------------------------------------------

extern "C" void kernel_launch(void* const* d_in, const int* in_sizes, int n_in,
                              void* d_out, int out_size, void* d_ws, size_t ws_size,
                              hipStream_t stream) {
  const float* src = (const float*)d_in[0];
  const int* action = (const int*)d_in[1];
  const int* type_ids = (const int*)d_in[2];
  const float* W_ih = (const float*)d_in[3];
  const float* b_ih = (const float*)d_in[4];
  const float* W_hh = (const float*)d_in[5];
  const float* b_hh = (const float*)d_in[6];
  const float* W_att = (const float*)d_in[7];
  const float* W_av = (const float*)d_in[8];
  const float* W_qa = (const float*)d_in[9];
  const float* b_qa = (const float*)d_in[10];
  const float* prod_emb = (const float*)d_in[11];
  const float* prod_bias = (const float*)d_in[12];
  const float* type_emb = (const float*)d_in[13];
  const float* W_init = (const float*)d_in[14];
  const float* b_init = (const float*)d_in[15];
  float* out = (float*)d_out;

  const size_t NEED_SMALL = 40943616ull;
  const size_t NEED_BIG = 309379072ull;
  bool big = ws_size >= NEED_BIG;
  if (!big && ws_size < NEED_SMALL) return;

  char* w = (char*)d_ws;
  size_t o = 0;
  unsigned short* wcat = (unsigned short*)(w + o); o += 18874368ull;
  unsigned short* wattT = (unsigned short*)(w + o); o += 2097152ull;
  unsigned short* wav = (unsigned short*)(w + o); o += 4194304ull;
  float* wqaT = (float*)(w + o); o += 524288ull;
  unsigned short* xaty = (unsigned short*)(w + o); o += 6291456ull;
  unsigned short* xstate0 = (unsigned short*)(w + o); o += 1048576ull;
  unsigned short* xstate1 = (unsigned short*)(w + o); o += 1048576ull;
  unsigned short* a2 = (unsigned short*)(w + o); o += 1048576ull;
  float* cbuf = (float*)(w + o); o += 1048576ull;
  float* qbuf = (float*)(w + o); o += 1048576ull;
  float* attf = (float*)(w + o); o += 1048576ull;
  unsigned short* pooledb = (unsigned short*)(w + o); o += 524288ull;
  unsigned short* winitb = (unsigned short*)(w + o); o += 2097152ull;
  float* bsum = (float*)(w + o); o += 16384ull;
  unsigned* flags = (unsigned*)(w + o); o += 32768ull;  // 256 blocks x 128B
  unsigned short* srcb = nullptr;
  if (big) { srcb = (unsigned short*)(w + o); o += 268435456ull; }

  // ---- prep ----
  if (big) pool_convert<1><<<1024, 256, 0, stream>>>(src, srcb, pooledb);
  else     pool_convert<0><<<1024, 256, 0, stream>>>(src, nullptr, pooledb);
  conv_wcat<<<36864, 256, 0, stream>>>(W_ih, W_hh, wcat);
  conv_bsum<<<16, 256, 0, stream>>>(b_ih, b_hh, bsum);
  conv_wattT<<<4096, 256, 0, stream>>>(W_att, wattT);
  conv_f2b<<<8192, 256, 0, stream>>>(W_av, wav, 2097152);
  conv_f2b<<<4096, 256, 0, stream>>>(W_init, winitb, 1048576);
  conv_wqaT<<<512, 256, 0, stream>>>(W_qa, wqaT);
  conv_xaty<<<12288, 256, 0, stream>>>(action, type_ids, prod_emb, type_emb, xaty);
  init0<<<1024, 256, 0, stream>>>(xstate0, cbuf, flags);
  gemm_bt<2, 1024><<<dim3(16, 4), 256, 0, stream>>>(pooledb, 1024, winitb, 1024,
                                                    nullptr, 0, b_init, xstate0, 2048, 1024);

  // ---- 48 steps, one node each (readout(t-1) rides phase A wave 4) ----
  for (int t = 0; t < 48; ++t) {
    const unsigned short* xin = (t & 1) ? xstate1 : xstate0;
    unsigned short* xout = (t & 1) ? xstate0 : xstate1;
    if (big)
      step_kernel<1><<<256, 512, 0, stream>>>(srcb, nullptr, xin, xout,
                                              xaty + (size_t)t * 65536, wcat, bsum, cbuf,
                                              a2, qbuf, wattT, wav, attf, wqaT, b_qa,
                                              prod_emb, prod_bias, out, flags, t);
    else
      step_kernel<0><<<256, 512, 0, stream>>>(nullptr, src, xin, xout,
                                              xaty + (size_t)t * 65536, wcat, bsum, cbuf,
                                              a2, qbuf, wattT, wav, attf, wqaT, b_qa,
                                              prod_emb, prod_bias, out, flags, t);
  }
  readout<<<256, 128, 0, stream>>>(attf, wqaT, b_qa, prod_emb, prod_bias, out, 47);
}

// Round 7
// 10626.939 us; speedup vs baseline: 1.2053x; 1.0749x over previous
//
#include <hip/hip_runtime.h>

// ---------------------------------------------------------------------------
// SQLDecoder: 48-step recurrent decoder. 3 nodes/step:
//   N1 gates GEMM + fused LSTM (+ readout(t-1) grid plane)
//   N2 flashq: q = h@W_att prologue (per-block matvec) + single-pass
//      online-softmax attention (K==V==src)
//   N3 att = tanh([h|ctx]@W_av^T) (+ bf16 into next xstate)
// src cached bf16 with SPLIT cache policy: rows 0-255 cacheable (L3-resident,
// 128MB + ~30MB weights < 256MB L3), rows 256-511 non-temporal (HBM stream).
// B=256 S=512 E=H=AV=1024 T=48 NP=97 K_state=2048 K_cat=2304
// ---------------------------------------------------------------------------

typedef short s16x8 __attribute__((ext_vector_type(8)));
typedef float f32x4 __attribute__((ext_vector_type(4)));

__device__ __forceinline__ unsigned short f2b(float x) {
  unsigned int u = __float_as_uint(x);
  return (unsigned short)((u + 0x7fffu + ((u >> 16) & 1u)) >> 16);  // RNE
}
__device__ __forceinline__ float b2f(unsigned short h) {
  return __uint_as_float(((unsigned int)h) << 16);
}
__device__ __forceinline__ float sigm(float x) { return 1.f / (1.f + __expf(-x)); }

template <int NT>
__device__ __forceinline__ s16x8 ld8(const s16x8* p) {
  if constexpr (NT) return __builtin_nontemporal_load(p);
  else return *p;
}
template <int NT>
__device__ __forceinline__ f32x4 ld4f(const f32x4* p) {
  if constexpr (NT) return __builtin_nontemporal_load(p);
  else return *p;
}

// ---------------- prep kernels ----------------------------------------------

// max-pool over s + bf16 src copy with split cache policy.
template <int WRITE_B16>
__global__ __launch_bounds__(256) void pool_convert(const float* __restrict__ src,
                                                    unsigned short* __restrict__ srcb,
                                                    unsigned short* __restrict__ pooledb) {
  int b = blockIdx.x >> 2;
  int e = (blockIdx.x & 3) * 256 + threadIdx.x;
  const float* p = src + (size_t)b * 524288 + e;
  float m = -3e38f;
  for (int s = 0; s < 512; s += 8) {
    float v[8];
#pragma unroll
    for (int i = 0; i < 8; ++i) v[i] = __builtin_nontemporal_load(p + (size_t)(s + i) * 1024);
#pragma unroll
    for (int i = 0; i < 8; ++i) {
      m = fmaxf(m, v[i]);
      if (WRITE_B16) {
        unsigned short bv = f2b(v[i]);
        unsigned short* dst = srcb + (size_t)b * 524288 + (size_t)(s + i) * 1024 + e;
        if (s + i < 256) *dst = bv;                       // cacheable half (L3)
        else __builtin_nontemporal_store(bv, dst);        // streamed half
      }
    }
  }
  pooledb[b * 1024 + e] = f2b(m);
}

// Wcat rows permuted n' = j*4+g (g: 0=i,1=f,2=g,3=o); cols = [att|h|a|ty].
__global__ __launch_bounds__(256) void conv_wcat(const float* __restrict__ wih,
                                                 const float* __restrict__ whh,
                                                 unsigned short* __restrict__ wcat) {
  int idx = blockIdx.x * 256 + threadIdx.x;  // 4096*2304
  int np = idx / 2304;
  int k = idx - np * 2304;
  int j = np >> 2, g = np & 3;
  int n = g * 1024 + j;
  float v;
  if (k < 1024) v = wih[n * 1280 + 128 + k];
  else if (k < 2048) v = whh[n * 1024 + (k - 1024)];
  else if (k < 2176) v = wih[n * 1280 + (k - 2048)];
  else v = wih[n * 1280 + 1152 + (k - 2176)];
  wcat[idx] = f2b(v);
}

__global__ __launch_bounds__(256) void conv_bsum(const float* __restrict__ bih,
                                                 const float* __restrict__ bhh,
                                                 float* __restrict__ bsum) {
  int idx = blockIdx.x * 256 + threadIdx.x;  // 4096
  int j = idx >> 2, g = idx & 3;
  int n = g * 1024 + j;
  bsum[idx] = bih[n] + bhh[n];
}

__global__ __launch_bounds__(256) void conv_wattT(const float* __restrict__ watt,
                                                  unsigned short* __restrict__ wt) {
  int idx = blockIdx.x * 256 + threadIdx.x;  // 1024*1024
  int e = idx >> 10, h = idx & 1023;
  wt[idx] = f2b(watt[h * 1024 + e]);
}

__global__ __launch_bounds__(256) void conv_f2b(const float* __restrict__ s,
                                                unsigned short* __restrict__ d, int n) {
  int idx = blockIdx.x * 256 + threadIdx.x;
  if (idx < n) d[idx] = f2b(s[idx]);
}

__global__ __launch_bounds__(256) void conv_wqaT(const float* __restrict__ wqa,
                                                 float* __restrict__ wt) {
  int idx = blockIdx.x * 256 + threadIdx.x;  // 131072
  int k = idx >> 7, j = idx & 127;
  wt[idx] = wqa[j * 1024 + k];
}

__global__ __launch_bounds__(256) void conv_xaty(const int* __restrict__ action,
                                                 const int* __restrict__ type_ids,
                                                 const float* __restrict__ prod_emb,
                                                 const float* __restrict__ type_emb,
                                                 unsigned short* __restrict__ xaty) {
  int idx = blockIdx.x * 256 + threadIdx.x;  // 48*256*256
  int t = idx >> 16;
  int b = (idx >> 8) & 255;
  int kk = idx & 255;
  float v = 0.f;
  if (t > 0) {
    if (kk < 128) v = prod_emb[action[t * 256 + b] * 128 + kk];
    else v = type_emb[type_ids[t * 256 + b] * 128 + (kk - 128)];
  }
  xaty[idx] = f2b(v);
}

__global__ __launch_bounds__(256) void init0(unsigned short* __restrict__ xs0,
                                             float* __restrict__ c) {
  int idx = blockIdx.x * 256 + threadIdx.x;  // 262144
  int b = idx >> 10, e = idx & 1023;
  xs0[(size_t)b * 2048 + e] = 0;
  c[idx] = 0.f;
}

// ---------------- GEMM 64x64 (h0 prep only) ---------------------------------
template <int EPI, int K>
__global__ __launch_bounds__(256) void gemm_bt(const unsigned short* __restrict__ A, int lda,
                                               const unsigned short* __restrict__ B, int ldb,
                                               float* __restrict__ C, int ldc,
                                               const float* __restrict__ bias,
                                               unsigned short* __restrict__ aux, int aux_ld,
                                               int aux_off) {
  int lane = threadIdx.x & 63;
  int wid = threadIdx.x >> 6;
  int mw = blockIdx.y * 64 + (wid >> 1) * 32;
  int nw = blockIdx.x * 64 + (wid & 1) * 32;
  int lr = lane & 15;
  int kg = lane >> 4;
  const unsigned short* a0p = A + (size_t)(mw + lr) * lda + kg * 8;
  const unsigned short* a1p = a0p + (size_t)16 * lda;
  const unsigned short* b0p = B + (size_t)(nw + lr) * ldb + kg * 8;
  const unsigned short* b1p = b0p + (size_t)16 * ldb;
  f32x4 acc00 = {0.f, 0.f, 0.f, 0.f};
  f32x4 acc01 = acc00, acc10 = acc00, acc11 = acc00;
#pragma unroll 4
  for (int k = 0; k < K; k += 32) {
    s16x8 a0 = *(const s16x8*)(a0p + k);
    s16x8 a1 = *(const s16x8*)(a1p + k);
    s16x8 b0 = *(const s16x8*)(b0p + k);
    s16x8 b1 = *(const s16x8*)(b1p + k);
    acc00 = __builtin_amdgcn_mfma_f32_16x16x32_bf16(a0, b0, acc00, 0, 0, 0);
    acc01 = __builtin_amdgcn_mfma_f32_16x16x32_bf16(a0, b1, acc01, 0, 0, 0);
    acc10 = __builtin_amdgcn_mfma_f32_16x16x32_bf16(a1, b0, acc10, 0, 0, 0);
    acc11 = __builtin_amdgcn_mfma_f32_16x16x32_bf16(a1, b1, acc11, 0, 0, 0);
  }
  int r0 = mw + kg * 4;
  int c0 = nw + lr;
#pragma unroll
  for (int fi = 0; fi < 2; ++fi) {
#pragma unroll
    for (int fj = 0; fj < 2; ++fj) {
      f32x4 acc = (fi == 0) ? (fj == 0 ? acc00 : acc01) : (fj == 0 ? acc10 : acc11);
      int rr = r0 + fi * 16;
      int cc = c0 + fj * 16;
#pragma unroll
      for (int r = 0; r < 4; ++r) {
        float v = acc[r];
        if constexpr (EPI == 2) v = tanhf(v + bias[cc]);
        if constexpr (EPI == 1) v = tanhf(v);
        if constexpr (EPI != 0) aux[(size_t)(rr + r) * aux_ld + aux_off + cc] = f2b(v);
        if constexpr (EPI != 2) C[(size_t)(rr + r) * ldc + cc] = v;
      }
    }
  }
}

// ---------------- GEMM 32x32 (att) ------------------------------------------
template <int EPI, int K>
__global__ __launch_bounds__(256) void gemm32(const unsigned short* __restrict__ A, int lda,
                                              const unsigned short* __restrict__ B, int ldb,
                                              float* __restrict__ C, int ldc,
                                              unsigned short* __restrict__ aux, int aux_ld,
                                              int aux_off) {
  int lane = threadIdx.x & 63;
  int wid = threadIdx.x >> 6;
  int mw = blockIdx.y * 32 + (wid >> 1) * 16;
  int nw = blockIdx.x * 32 + (wid & 1) * 16;
  int lr = lane & 15;
  int kg = lane >> 4;
  const unsigned short* ap = A + (size_t)(mw + lr) * lda + kg * 8;
  const unsigned short* bp = B + (size_t)(nw + lr) * ldb + kg * 8;
  f32x4 acc = {0.f, 0.f, 0.f, 0.f};
#pragma unroll 8
  for (int k = 0; k < K; k += 32) {
    s16x8 a = *(const s16x8*)(ap + k);
    s16x8 b = *(const s16x8*)(bp + k);
    acc = __builtin_amdgcn_mfma_f32_16x16x32_bf16(a, b, acc, 0, 0, 0);
  }
  int rr = mw + kg * 4;
  int cc = nw + lr;
#pragma unroll
  for (int r = 0; r < 4; ++r) {
    float v = acc[r];
    if constexpr (EPI == 1) {
      v = tanhf(v);
      aux[(size_t)(rr + r) * aux_ld + aux_off + cc] = f2b(v);
    }
    C[(size_t)(rr + r) * ldc + cc] = v;
  }
}

// ---------------- N1: gates GEMM + fused LSTM + piggybacked readout(t-1) ----
// grid (64,5): y<4 GEMM+LSTM (tile 64b x 64gate), y==4: readout for t-1.
__global__ __launch_bounds__(256) void gates_fused(const unsigned short* __restrict__ xin,
                                                   const unsigned short* __restrict__ xaty,
                                                   const unsigned short* __restrict__ wcat,
                                                   const float* __restrict__ bsum,
                                                   float* __restrict__ cbuf,
                                                   unsigned short* __restrict__ xout,
                                                   unsigned short* __restrict__ a2,
                                                   const float* __restrict__ attf,
                                                   const float* __restrict__ wqaT,
                                                   const float* __restrict__ b_qa,
                                                   const float* __restrict__ prod_emb,
                                                   const float* __restrict__ prod_bias,
                                                   float* __restrict__ out, int t) {
  __shared__ float ld[64][68];
  __shared__ float s_att[2][1024];
  __shared__ float s_q2[2][128];
  __shared__ float s_log[2][100];
  __shared__ float s_red[2][2];

  if (blockIdx.y == 4) {
    if (t == 0) return;
    int half = threadIdx.x >> 7;
    int ltid = threadIdx.x & 127;
#pragma unroll
    for (int rep = 0; rep < 2; ++rep) {
      int b = blockIdx.x * 4 + rep * 2 + half;
      const float* ap = attf + (size_t)b * 1024;
      for (int i = ltid; i < 1024; i += 128) s_att[half][i] = ap[i];
      __syncthreads();
      float acc = b_qa[ltid];
      for (int k = 0; k < 1024; ++k) acc += s_att[half][k] * wqaT[k * 128 + ltid];
      s_q2[half][ltid] = tanhf(acc);
      __syncthreads();
      if (ltid < 97) {
        float a = prod_bias[ltid];
        const float* pe = prod_emb + ltid * 128;
        float aa = 0.f;
        for (int k = 0; k < 128; ++k) aa += s_q2[half][k] * pe[k];
        s_log[half][ltid] = a + aa;
      }
      __syncthreads();
      if (ltid == 0) {
        float M = s_log[half][0];
        for (int k2 = 1; k2 < 97; ++k2) M = fmaxf(M, s_log[half][k2]);
        float D = 0.f;
        for (int k2 = 0; k2 < 97; ++k2) D += __expf(s_log[half][k2] - M);
        s_red[half][0] = M;
        s_red[half][1] = D;
      }
      __syncthreads();
      if (ltid < 97)
        out[((size_t)(t - 1) * 256 + b) * 97 + ltid] =
            __expf(s_log[half][ltid] - s_red[half][0]) / s_red[half][1];
      __syncthreads();
    }
    return;
  }

  int lane = threadIdx.x & 63;
  int wid = threadIdx.x >> 6;
  int mwl = (wid >> 1) * 32;
  int nwl = (wid & 1) * 32;
  int mw = blockIdx.y * 64 + mwl;
  int nw = blockIdx.x * 64 + nwl;
  int lr = lane & 15;
  int kg = lane >> 4;
  const unsigned short* a0p = xin + (size_t)(mw + lr) * 2048 + kg * 8;
  const unsigned short* a1p = a0p + (size_t)16 * 2048;
  const unsigned short* b0p = wcat + (size_t)(nw + lr) * 2304 + kg * 8;
  const unsigned short* b1p = b0p + (size_t)16 * 2304;
  f32x4 acc00 = {0.f, 0.f, 0.f, 0.f};
  f32x4 acc01 = acc00, acc10 = acc00, acc11 = acc00;
#pragma unroll 8
  for (int k = 0; k < 2048; k += 32) {
    s16x8 a0 = *(const s16x8*)(a0p + k);
    s16x8 a1 = *(const s16x8*)(a1p + k);
    s16x8 b0 = *(const s16x8*)(b0p + k);
    s16x8 b1 = *(const s16x8*)(b1p + k);
    acc00 = __builtin_amdgcn_mfma_f32_16x16x32_bf16(a0, b0, acc00, 0, 0, 0);
    acc01 = __builtin_amdgcn_mfma_f32_16x16x32_bf16(a0, b1, acc01, 0, 0, 0);
    acc10 = __builtin_amdgcn_mfma_f32_16x16x32_bf16(a1, b0, acc10, 0, 0, 0);
    acc11 = __builtin_amdgcn_mfma_f32_16x16x32_bf16(a1, b1, acc11, 0, 0, 0);
  }
  const unsigned short* c0p = xaty + (size_t)(mw + lr) * 256 + kg * 8;
  const unsigned short* c1p = c0p + (size_t)16 * 256;
#pragma unroll
  for (int k = 0; k < 256; k += 32) {
    s16x8 a0 = *(const s16x8*)(c0p + k);
    s16x8 a1 = *(const s16x8*)(c1p + k);
    s16x8 b0 = *(const s16x8*)(b0p + 2048 + k);
    s16x8 b1 = *(const s16x8*)(b1p + 2048 + k);
    acc00 = __builtin_amdgcn_mfma_f32_16x16x32_bf16(a0, b0, acc00, 0, 0, 0);
    acc01 = __builtin_amdgcn_mfma_f32_16x16x32_bf16(a0, b1, acc01, 0, 0, 0);
    acc10 = __builtin_amdgcn_mfma_f32_16x16x32_bf16(a1, b0, acc10, 0, 0, 0);
    acc11 = __builtin_amdgcn_mfma_f32_16x16x32_bf16(a1, b1, acc11, 0, 0, 0);
  }
  int r0 = mwl + kg * 4;
  int c0 = nwl + lr;
#pragma unroll
  for (int fi = 0; fi < 2; ++fi)
#pragma unroll
    for (int fj = 0; fj < 2; ++fj) {
      f32x4 acc = (fi == 0) ? (fj == 0 ? acc00 : acc01) : (fj == 0 ? acc10 : acc11);
#pragma unroll
      for (int r = 0; r < 4; ++r) ld[r0 + fi * 16 + r][c0 + fj * 16] = acc[r];
    }
  __syncthreads();
  int row = threadIdx.x >> 2;
  int col0 = (threadIdx.x & 3) * 16;
  int b = blockIdx.y * 64 + row;
  int jbase = blockIdx.x * 16 + (threadIdx.x & 3) * 4;
  float4 cold = *(const float4*)(cbuf + (size_t)b * 1024 + jbase);
  float cn[4];
  unsigned short hb[4];
#pragma unroll
  for (int i = 0; i < 4; ++i) {
    float4 bs = *(const float4*)(bsum + (size_t)(jbase + i) * 4);
    float vi = ld[row][col0 + 4 * i + 0] + bs.x;
    float vf = ld[row][col0 + 4 * i + 1] + bs.y;
    float vg = ld[row][col0 + 4 * i + 2] + bs.z;
    float vo = ld[row][col0 + 4 * i + 3] + bs.w;
    float co = (i == 0) ? cold.x : (i == 1) ? cold.y : (i == 2) ? cold.z : cold.w;
    float ct = sigm(vf) * co + sigm(vi) * tanhf(vg);
    float ht = sigm(vo) * tanhf(ct);
    cn[i] = ct;
    hb[i] = f2b(ht);
  }
  *(float4*)(cbuf + (size_t)b * 1024 + jbase) = make_float4(cn[0], cn[1], cn[2], cn[3]);
  ushort4 h4 = make_ushort4(hb[0], hb[1], hb[2], hb[3]);
  *(ushort4*)(xout + (size_t)b * 2048 + 1024 + jbase) = h4;
  *(ushort4*)(a2 + (size_t)b * 2048 + jbase) = h4;
}

// ---------------- N2: fused q-projection + flash attention ------------------
template <int NT>
__device__ __forceinline__ void stream_bf16(const unsigned short* rb, int s0,
                                            const float* qr, float& m, float& d,
                                            float* ctx) {
  s16x8 c0 = ld8<NT>((const s16x8*)(rb + (size_t)s0 * 1024));
  s16x8 c1 = ld8<NT>((const s16x8*)(rb + (size_t)s0 * 1024 + 8));
  s16x8 d0 = ld8<NT>((const s16x8*)(rb + (size_t)(s0 + 1) * 1024));
  s16x8 d1 = ld8<NT>((const s16x8*)(rb + (size_t)(s0 + 1) * 1024 + 8));
  for (int s = 0; s < 64; ++s) {
    int rn = s0 + s + 2;
    rn = rn > 511 ? 511 : rn;
    s16x8 e0 = ld8<NT>((const s16x8*)(rb + (size_t)rn * 1024));
    s16x8 e1 = ld8<NT>((const s16x8*)(rb + (size_t)rn * 1024 + 8));
    float v[16];
#pragma unroll
    for (int i = 0; i < 8; ++i) {
      v[i] = b2f((unsigned short)c0[i]);
      v[8 + i] = b2f((unsigned short)c1[i]);
    }
    float sc = 0.f;
#pragma unroll
    for (int i = 0; i < 16; ++i) sc += v[i] * qr[i];
#pragma unroll
    for (int off = 1; off < 64; off <<= 1) sc += __shfl_xor(sc, off);
    float mn = fmaxf(m, sc);
    float scale = __expf(m - mn);
    float wgt = __expf(sc - mn);
    d = d * scale + wgt;
#pragma unroll
    for (int i = 0; i < 16; ++i) ctx[i] = ctx[i] * scale + wgt * v[i];
    m = mn;
    c0 = d0; c1 = d1; d0 = e0; d1 = e1;
  }
}

template <int NT>
__device__ __forceinline__ void stream_f32(const float* rf, int s0, const float* qr,
                                           float& m, float& d, float* ctx) {
  for (int s = 0; s < 64; ++s) {
    int rr = s0 + s;
    float v[16];
#pragma unroll
    for (int i = 0; i < 4; ++i) {
      f32x4 tq = ld4f<NT>((const f32x4*)(rf + (size_t)rr * 1024 + 4 * i));
      v[4 * i] = tq[0]; v[4 * i + 1] = tq[1]; v[4 * i + 2] = tq[2]; v[4 * i + 3] = tq[3];
    }
    float sc = 0.f;
#pragma unroll
    for (int i = 0; i < 16; ++i) sc += v[i] * qr[i];
#pragma unroll
    for (int off = 1; off < 64; off <<= 1) sc += __shfl_xor(sc, off);
    float mn = fmaxf(m, sc);
    float scale = __expf(m - mn);
    float wgt = __expf(sc - mn);
    d = d * scale + wgt;
#pragma unroll
    for (int i = 0; i < 16; ++i) ctx[i] = ctx[i] * scale + wgt * v[i];
    m = mn;
  }
}

template <int BF16P>
__global__ __launch_bounds__(512) void flashq(const unsigned short* __restrict__ srcb,
                                              const float* __restrict__ srcf,
                                              const unsigned short* __restrict__ wattT,
                                              unsigned short* __restrict__ a2) {
  union SMem {
    struct { float q[1024]; unsigned short h[1024]; } p;
    struct { unsigned short lctx[8][1024]; float lm[8], ldn[8], lsc[8], sDinv; } c;
  };
  __shared__ SMem sm;
  const int tid = threadIdx.x;
  const int lane = tid & 63;
  const int wv = tid >> 6;  // 0..7
  const int b = blockIdx.x;
  const int s0 = wv * 64;

  // ---- prologue: q = h @ W_att (each thread: 2 outputs, 1024-MAC) ----
  sm.p.h[tid] = a2[(size_t)b * 2048 + tid];
  sm.p.h[tid + 512] = a2[(size_t)b * 2048 + tid + 512];
  __syncthreads();
  {
    const unsigned short* w0 = wattT + (size_t)(2 * tid) * 1024;
    const unsigned short* w1 = w0 + 1024;
    float acc0 = 0.f, acc1 = 0.f;
    for (int k = 0; k < 1024; k += 8) {
      s16x8 hv = *(const s16x8*)(sm.p.h + k);
      s16x8 wa = *(const s16x8*)(w0 + k);
      s16x8 wb = *(const s16x8*)(w1 + k);
#pragma unroll
      for (int i = 0; i < 8; ++i) {
        float hf = b2f((unsigned short)hv[i]);
        acc0 += hf * b2f((unsigned short)wa[i]);
        acc1 += hf * b2f((unsigned short)wb[i]);
      }
    }
    sm.p.q[2 * tid] = acc0;
    sm.p.q[2 * tid + 1] = acc1;
  }
  __syncthreads();
  float qr[16];
#pragma unroll
  for (int i = 0; i < 16; ++i) qr[i] = sm.p.q[lane * 16 + i];
  __syncthreads();  // release LDS for the c-union

  // ---- stream: waves 0-3 cacheable rows 0-255, waves 4-7 nt rows 256-511 ----
  float m = -3e38f, d = 0.f;
  float ctx[16];
#pragma unroll
  for (int i = 0; i < 16; ++i) ctx[i] = 0.f;
  if (BF16P) {
    const unsigned short* rb = srcb + (size_t)b * 524288 + lane * 16;
    if (wv < 4) stream_bf16<0>(rb, s0, qr, m, d, ctx);
    else        stream_bf16<1>(rb, s0, qr, m, d, ctx);
  } else {
    const float* rf = srcf + (size_t)b * 524288 + lane * 16;
    if (wv < 4) stream_f32<0>(rf, s0, qr, m, d, ctx);
    else        stream_f32<1>(rf, s0, qr, m, d, ctx);
  }

  // ---- cross-wave combine ----
#pragma unroll
  for (int i = 0; i < 16; ++i) sm.c.lctx[wv][lane * 16 + i] = f2b(ctx[i]);
  if (lane == 0) { sm.c.lm[wv] = m; sm.c.ldn[wv] = d; }
  __syncthreads();
  if (tid == 0) {
    float M = sm.c.lm[0];
    for (int w2 = 1; w2 < 8; ++w2) M = fmaxf(M, sm.c.lm[w2]);
    float D = 0.f;
    for (int w2 = 0; w2 < 8; ++w2) {
      float sc = __expf(sm.c.lm[w2] - M);
      sm.c.lsc[w2] = sc;
      D += sc * sm.c.ldn[w2];
    }
    sm.c.sDinv = 1.f / D;
  }
  __syncthreads();
#pragma unroll
  for (int half = 0; half < 2; ++half) {
    int e = tid + half * 512;
    float acc2 = 0.f;
#pragma unroll
    for (int w2 = 0; w2 < 8; ++w2) acc2 += sm.c.lsc[w2] * b2f(sm.c.lctx[w2][e]);
    a2[(size_t)b * 2048 + 1024 + e] = f2b(acc2 * sm.c.sDinv);
  }
}

// ---------------- standalone readout (final step) ----------------------------
__global__ __launch_bounds__(128) void readout(const float* __restrict__ att,
                                               const float* __restrict__ wqaT,
                                               const float* __restrict__ b_qa,
                                               const float* __restrict__ prod_emb,
                                               const float* __restrict__ prod_bias,
                                               float* __restrict__ out, int t) {
  __shared__ float s_att[1024], s_q2[128], s_log[97], s_red[2];
  int b = blockIdx.x;
  int tid = threadIdx.x;
  for (int i = tid; i < 1024; i += 128) s_att[i] = att[(size_t)b * 1024 + i];
  __syncthreads();
  float acc = b_qa[tid];
  for (int k = 0; k < 1024; ++k) acc += s_att[k] * wqaT[k * 128 + tid];
  s_q2[tid] = tanhf(acc);
  __syncthreads();
  if (tid < 97) {
    float a = prod_bias[tid];
    const float* pe = prod_emb + tid * 128;
    for (int k = 0; k < 128; ++k) a += s_q2[k] * pe[k];
    s_log[tid] = a;
  }
  __syncthreads();
  if (tid == 0) {
    float M = s_log[0];
    for (int k = 1; k < 97; ++k) M = fmaxf(M, s_log[k]);
    float D = 0.f;
    for (int k = 0; k < 97; ++k) D += __expf(s_log[k] - M);
    s_red[0] = M;
    s_red[1] = D;
  }
  __syncthreads();
  if (tid < 97)
    out[((size_t)t * 256 + b) * 97 + tid] = __expf(s_log[tid] - s_red[0]) / s_red[1];
}

// ---------------------------------------------------------------------------

extern "C" void kernel_launch(void* const* d_in, const int* in_sizes, int n_in,
                              void* d_out, int out_size, void* d_ws, size_t ws_size,
                              hipStream_t stream) {
  const float* src = (const float*)d_in[0];
  const int* action = (const int*)d_in[1];
  const int* type_ids = (const int*)d_in[2];
  const float* W_ih = (const float*)d_in[3];
  const float* b_ih = (const float*)d_in[4];
  const float* W_hh = (const float*)d_in[5];
  const float* b_hh = (const float*)d_in[6];
  const float* W_att = (const float*)d_in[7];
  const float* W_av = (const float*)d_in[8];
  const float* W_qa = (const float*)d_in[9];
  const float* b_qa = (const float*)d_in[10];
  const float* prod_emb = (const float*)d_in[11];
  const float* prod_bias = (const float*)d_in[12];
  const float* type_emb = (const float*)d_in[13];
  const float* W_init = (const float*)d_in[14];
  const float* b_init = (const float*)d_in[15];
  float* out = (float*)d_out;

  const size_t NEED_SMALL = 39862272ull;
  const size_t NEED_BIG = 308297728ull;
  bool big = ws_size >= NEED_BIG;
  if (!big && ws_size < NEED_SMALL) return;

  char* w = (char*)d_ws;
  size_t o = 0;
  unsigned short* wcat = (unsigned short*)(w + o); o += 18874368ull;
  unsigned short* wattT = (unsigned short*)(w + o); o += 2097152ull;
  unsigned short* wav = (unsigned short*)(w + o); o += 4194304ull;
  float* wqaT = (float*)(w + o); o += 524288ull;
  unsigned short* xaty = (unsigned short*)(w + o); o += 6291456ull;
  unsigned short* xstate0 = (unsigned short*)(w + o); o += 1048576ull;
  unsigned short* xstate1 = (unsigned short*)(w + o); o += 1048576ull;
  unsigned short* a2 = (unsigned short*)(w + o); o += 1048576ull;
  float* cbuf = (float*)(w + o); o += 1048576ull;
  float* attf = (float*)(w + o); o += 1048576ull;
  unsigned short* pooledb = (unsigned short*)(w + o); o += 524288ull;
  unsigned short* winitb = (unsigned short*)(w + o); o += 2097152ull;
  float* bsum = (float*)(w + o); o += 16384ull;
  unsigned short* srcb = nullptr;
  if (big) { srcb = (unsigned short*)(w + o); o += 268435456ull; }

  // ---- prep ----
  if (big) pool_convert<1><<<1024, 256, 0, stream>>>(src, srcb, pooledb);
  else     pool_convert<0><<<1024, 256, 0, stream>>>(src, nullptr, pooledb);
  conv_wcat<<<36864, 256, 0, stream>>>(W_ih, W_hh, wcat);
  conv_bsum<<<16, 256, 0, stream>>>(b_ih, b_hh, bsum);
  conv_wattT<<<4096, 256, 0, stream>>>(W_att, wattT);
  conv_f2b<<<8192, 256, 0, stream>>>(W_av, wav, 2097152);
  conv_f2b<<<4096, 256, 0, stream>>>(W_init, winitb, 1048576);
  conv_wqaT<<<512, 256, 0, stream>>>(W_qa, wqaT);
  conv_xaty<<<12288, 256, 0, stream>>>(action, type_ids, prod_emb, type_emb, xaty);
  init0<<<1024, 256, 0, stream>>>(xstate0, cbuf);
  gemm_bt<2, 1024><<<dim3(16, 4), 256, 0, stream>>>(pooledb, 1024, winitb, 1024,
                                                    nullptr, 0, b_init, xstate0, 2048, 1024);

  // ---- 48 steps x 3 nodes (readout(t-1) rides gates(t)) ----
  for (int t = 0; t < 48; ++t) {
    const unsigned short* xin = (t & 1) ? xstate1 : xstate0;
    unsigned short* xout = (t & 1) ? xstate0 : xstate1;
    gates_fused<<<dim3(64, 5), 256, 0, stream>>>(xin, xaty + (size_t)t * 65536, wcat, bsum,
                                                 cbuf, xout, a2, attf, wqaT, b_qa, prod_emb,
                                                 prod_bias, out, t);
    if (big) flashq<1><<<256, 512, 0, stream>>>(srcb, nullptr, wattT, a2);
    else     flashq<0><<<256, 512, 0, stream>>>(nullptr, src, wattT, a2);
    gemm32<1, 2048><<<dim3(32, 8), 256, 0, stream>>>(a2, 2048, wav, 2048, attf, 1024,
                                                     xout, 2048, 0);
  }
  readout<<<256, 128, 0, stream>>>(attf, wqaT, b_qa, prod_emb, prod_bias, out, 47);
}

// Round 8
// 6821.497 us; speedup vs baseline: 1.8777x; 1.5579x over previous
//
#include <hip/hip_runtime.h>

// ---------------------------------------------------------------------------
// SQLDecoder: 48-step recurrent decoder with dot-product attention.
//   * scores = src @ (h @ W_att)  -- never materialize src_lin [B,S,H]
//   * single-pass online-softmax attention (K == V == src), src cached as bf16
//     and read with NON-TEMPORAL loads (src has no reuse; protects weights in L3)
//   * bf16 MFMA GEMMs, fp32 cell/readout; LSTM fused into gates-GEMM epilogue;
//     readout(t-1) folded into gates(t) launch as an extra grid plane
// B=256 S=512 E=H=AV=1024 A=TY=128 T=48 NP=97 K_state=2048 K_aty=256
// ---------------------------------------------------------------------------

typedef short s16x8 __attribute__((ext_vector_type(8)));
typedef float f32x4 __attribute__((ext_vector_type(4)));

__device__ __forceinline__ unsigned short f2b(float x) {
  unsigned int u = __float_as_uint(x);
  return (unsigned short)((u + 0x7fffu + ((u >> 16) & 1u)) >> 16);  // RNE
}
__device__ __forceinline__ float b2f(unsigned short h) {
  return __uint_as_float(((unsigned int)h) << 16);
}
__device__ __forceinline__ float sigm(float x) { return 1.f / (1.f + __expf(-x)); }

// ---------------- prep kernels ----------------------------------------------

template <int WRITE_B16>
__global__ __launch_bounds__(256) void pool_convert(const float* __restrict__ src,
                                                    unsigned short* __restrict__ srcb,
                                                    unsigned short* __restrict__ pooledb) {
  int b = blockIdx.x >> 2;
  int e = (blockIdx.x & 3) * 256 + threadIdx.x;
  const float* p = src + (size_t)b * 524288 + e;
  float m = -3e38f;
  for (int s = 0; s < 512; s += 8) {
    float v[8];
#pragma unroll
    for (int i = 0; i < 8; ++i) v[i] = __builtin_nontemporal_load(p + (size_t)(s + i) * 1024);
#pragma unroll
    for (int i = 0; i < 8; ++i) {
      m = fmaxf(m, v[i]);
      if (WRITE_B16)
        __builtin_nontemporal_store(f2b(v[i]),
                                    srcb + (size_t)b * 524288 + (size_t)(s + i) * 1024 + e);
    }
  }
  pooledb[b * 1024 + e] = f2b(m);
}

// Wcat rows permuted n' = j*4+g (g: 0=i,1=f,2=g,3=o); cols = [att|h|a|ty].
__global__ __launch_bounds__(256) void conv_wcat(const float* __restrict__ wih,
                                                 const float* __restrict__ whh,
                                                 unsigned short* __restrict__ wcat) {
  int idx = blockIdx.x * 256 + threadIdx.x;  // 4096*2304
  int np = idx / 2304;
  int k = idx - np * 2304;
  int j = np >> 2, g = np & 3;
  int n = g * 1024 + j;
  float v;
  if (k < 1024) v = wih[n * 1280 + 128 + k];
  else if (k < 2048) v = whh[n * 1024 + (k - 1024)];
  else if (k < 2176) v = wih[n * 1280 + (k - 2048)];
  else v = wih[n * 1280 + 1152 + (k - 2176)];
  wcat[idx] = f2b(v);
}

__global__ __launch_bounds__(256) void conv_bsum(const float* __restrict__ bih,
                                                 const float* __restrict__ bhh,
                                                 float* __restrict__ bsum) {
  int idx = blockIdx.x * 256 + threadIdx.x;  // 4096
  int j = idx >> 2, g = idx & 3;
  int n = g * 1024 + j;
  bsum[idx] = bih[n] + bhh[n];
}

__global__ __launch_bounds__(256) void conv_wattT(const float* __restrict__ watt,
                                                  unsigned short* __restrict__ wt) {
  int idx = blockIdx.x * 256 + threadIdx.x;  // 1024*1024
  int e = idx >> 10, h = idx & 1023;
  wt[idx] = f2b(watt[h * 1024 + e]);
}

__global__ __launch_bounds__(256) void conv_f2b(const float* __restrict__ s,
                                                unsigned short* __restrict__ d, int n) {
  int idx = blockIdx.x * 256 + threadIdx.x;
  if (idx < n) d[idx] = f2b(s[idx]);
}

__global__ __launch_bounds__(256) void conv_wqaT(const float* __restrict__ wqa,
                                                 float* __restrict__ wt) {
  int idx = blockIdx.x * 256 + threadIdx.x;  // 131072
  int k = idx >> 7, j = idx & 127;
  wt[idx] = wqa[j * 1024 + k];
}

__global__ __launch_bounds__(256) void conv_xaty(const int* __restrict__ action,
                                                 const int* __restrict__ type_ids,
                                                 const float* __restrict__ prod_emb,
                                                 const float* __restrict__ type_emb,
                                                 unsigned short* __restrict__ xaty) {
  int idx = blockIdx.x * 256 + threadIdx.x;  // 48*256*256
  int t = idx >> 16;
  int b = (idx >> 8) & 255;
  int kk = idx & 255;
  float v = 0.f;
  if (t > 0) {
    if (kk < 128) v = prod_emb[action[t * 256 + b] * 128 + kk];
    else v = type_emb[type_ids[t * 256 + b] * 128 + (kk - 128)];
  }
  xaty[idx] = f2b(v);
}

__global__ __launch_bounds__(256) void init0(unsigned short* __restrict__ xs0,
                                             float* __restrict__ c) {
  int idx = blockIdx.x * 256 + threadIdx.x;  // 262144
  int b = idx >> 10, e = idx & 1023;
  xs0[(size_t)b * 2048 + e] = 0;
  c[idx] = 0.f;
}

// ---------------- GEMM 64x64 (prep h0 only) ---------------------------------
template <int EPI, int K>
__global__ __launch_bounds__(256) void gemm_bt(const unsigned short* __restrict__ A, int lda,
                                               const unsigned short* __restrict__ B, int ldb,
                                               float* __restrict__ C, int ldc,
                                               const float* __restrict__ bias,
                                               unsigned short* __restrict__ aux, int aux_ld,
                                               int aux_off) {
  int lane = threadIdx.x & 63;
  int wid = threadIdx.x >> 6;
  int mw = blockIdx.y * 64 + (wid >> 1) * 32;
  int nw = blockIdx.x * 64 + (wid & 1) * 32;
  int lr = lane & 15;
  int kg = lane >> 4;
  const unsigned short* a0p = A + (size_t)(mw + lr) * lda + kg * 8;
  const unsigned short* a1p = a0p + (size_t)16 * lda;
  const unsigned short* b0p = B + (size_t)(nw + lr) * ldb + kg * 8;
  const unsigned short* b1p = b0p + (size_t)16 * ldb;
  f32x4 acc00 = {0.f, 0.f, 0.f, 0.f};
  f32x4 acc01 = acc00, acc10 = acc00, acc11 = acc00;
#pragma unroll 4
  for (int k = 0; k < K; k += 32) {
    s16x8 a0 = *(const s16x8*)(a0p + k);
    s16x8 a1 = *(const s16x8*)(a1p + k);
    s16x8 b0 = *(const s16x8*)(b0p + k);
    s16x8 b1 = *(const s16x8*)(b1p + k);
    acc00 = __builtin_amdgcn_mfma_f32_16x16x32_bf16(a0, b0, acc00, 0, 0, 0);
    acc01 = __builtin_amdgcn_mfma_f32_16x16x32_bf16(a0, b1, acc01, 0, 0, 0);
    acc10 = __builtin_amdgcn_mfma_f32_16x16x32_bf16(a1, b0, acc10, 0, 0, 0);
    acc11 = __builtin_amdgcn_mfma_f32_16x16x32_bf16(a1, b1, acc11, 0, 0, 0);
  }
  int r0 = mw + kg * 4;
  int c0 = nw + lr;
#pragma unroll
  for (int fi = 0; fi < 2; ++fi) {
#pragma unroll
    for (int fj = 0; fj < 2; ++fj) {
      f32x4 acc = (fi == 0) ? (fj == 0 ? acc00 : acc01) : (fj == 0 ? acc10 : acc11);
      int rr = r0 + fi * 16;
      int cc = c0 + fj * 16;
#pragma unroll
      for (int r = 0; r < 4; ++r) {
        float v = acc[r];
        if constexpr (EPI == 2) v = tanhf(v + bias[cc]);
        if constexpr (EPI == 1) v = tanhf(v);
        if constexpr (EPI != 0) aux[(size_t)(rr + r) * aux_ld + aux_off + cc] = f2b(v);
        if constexpr (EPI != 2) C[(size_t)(rr + r) * ldc + cc] = v;
      }
    }
  }
}

// ---------------- GEMM 32x32 (q and att: full-chip 256 blocks) --------------
template <int EPI, int K>
__global__ __launch_bounds__(256) void gemm32(const unsigned short* __restrict__ A, int lda,
                                              const unsigned short* __restrict__ B, int ldb,
                                              float* __restrict__ C, int ldc,
                                              unsigned short* __restrict__ aux, int aux_ld,
                                              int aux_off) {
  int lane = threadIdx.x & 63;
  int wid = threadIdx.x >> 6;
  int mw = blockIdx.y * 32 + (wid >> 1) * 16;
  int nw = blockIdx.x * 32 + (wid & 1) * 16;
  int lr = lane & 15;
  int kg = lane >> 4;
  const unsigned short* ap = A + (size_t)(mw + lr) * lda + kg * 8;
  const unsigned short* bp = B + (size_t)(nw + lr) * ldb + kg * 8;
  f32x4 acc = {0.f, 0.f, 0.f, 0.f};
#pragma unroll 8
  for (int k = 0; k < K; k += 32) {
    s16x8 a = *(const s16x8*)(ap + k);
    s16x8 b = *(const s16x8*)(bp + k);
    acc = __builtin_amdgcn_mfma_f32_16x16x32_bf16(a, b, acc, 0, 0, 0);
  }
  int rr = mw + kg * 4;
  int cc = nw + lr;
#pragma unroll
  for (int r = 0; r < 4; ++r) {
    float v = acc[r];
    if constexpr (EPI == 1) {
      v = tanhf(v);
      aux[(size_t)(rr + r) * aux_ld + aux_off + cc] = f2b(v);
    }
    C[(size_t)(rr + r) * ldc + cc] = v;
  }
}

// ---------------- gates GEMM + fused LSTM + piggybacked readout(t-1) --------
// grid (64,5): y<4 GEMM+LSTM (tile 64b x 64gate), y==4: readout for t-1.
__global__ __launch_bounds__(256) void gates_fused(const unsigned short* __restrict__ xin,
                                                   const unsigned short* __restrict__ xaty,
                                                   const unsigned short* __restrict__ wcat,
                                                   const float* __restrict__ bsum,
                                                   float* __restrict__ cbuf,
                                                   unsigned short* __restrict__ xout,
                                                   unsigned short* __restrict__ a2,
                                                   const float* __restrict__ attf,
                                                   const float* __restrict__ wqaT,
                                                   const float* __restrict__ b_qa,
                                                   const float* __restrict__ prod_emb,
                                                   const float* __restrict__ prod_bias,
                                                   float* __restrict__ out, int t) {
  __shared__ float ld[64][68];
  __shared__ float s_att[2][1024];
  __shared__ float s_q2[2][128];
  __shared__ float s_log[2][100];
  __shared__ float s_red[2][2];

  if (blockIdx.y == 4) {
    // ---- readout for step t-1, 4 batches per block ----
    if (t == 0) return;
    int half = threadIdx.x >> 7;
    int ltid = threadIdx.x & 127;
#pragma unroll
    for (int rep = 0; rep < 2; ++rep) {
      int b = blockIdx.x * 4 + rep * 2 + half;
      const float* ap = attf + (size_t)b * 1024;
      for (int i = ltid; i < 1024; i += 128) s_att[half][i] = ap[i];
      __syncthreads();
      float acc = b_qa[ltid];
      for (int k = 0; k < 1024; ++k) acc += s_att[half][k] * wqaT[k * 128 + ltid];
      s_q2[half][ltid] = tanhf(acc);
      __syncthreads();
      if (ltid < 97) {
        float a = prod_bias[ltid];
        const float* pe = prod_emb + ltid * 128;
        float aa = 0.f;
        for (int k = 0; k < 128; ++k) aa += s_q2[half][k] * pe[k];
        s_log[half][ltid] = a + aa;
      }
      __syncthreads();
      if (ltid == 0) {
        float M = s_log[half][0];
        for (int k2 = 1; k2 < 97; ++k2) M = fmaxf(M, s_log[half][k2]);
        float D = 0.f;
        for (int k2 = 0; k2 < 97; ++k2) D += __expf(s_log[half][k2] - M);
        s_red[half][0] = M;
        s_red[half][1] = D;
      }
      __syncthreads();
      if (ltid < 97)
        out[((size_t)(t - 1) * 256 + b) * 97 + ltid] =
            __expf(s_log[half][ltid] - s_red[half][0]) / s_red[half][1];
      __syncthreads();
    }
    return;
  }

  int lane = threadIdx.x & 63;
  int wid = threadIdx.x >> 6;
  int mwl = (wid >> 1) * 32;
  int nwl = (wid & 1) * 32;
  int mw = blockIdx.y * 64 + mwl;
  int nw = blockIdx.x * 64 + nwl;
  int lr = lane & 15;
  int kg = lane >> 4;
  const unsigned short* a0p = xin + (size_t)(mw + lr) * 2048 + kg * 8;
  const unsigned short* a1p = a0p + (size_t)16 * 2048;
  const unsigned short* b0p = wcat + (size_t)(nw + lr) * 2304 + kg * 8;
  const unsigned short* b1p = b0p + (size_t)16 * 2304;
  f32x4 acc00 = {0.f, 0.f, 0.f, 0.f};
  f32x4 acc01 = acc00, acc10 = acc00, acc11 = acc00;
#pragma unroll 8
  for (int k = 0; k < 2048; k += 32) {
    s16x8 a0 = *(const s16x8*)(a0p + k);
    s16x8 a1 = *(const s16x8*)(a1p + k);
    s16x8 b0 = *(const s16x8*)(b0p + k);
    s16x8 b1 = *(const s16x8*)(b1p + k);
    acc00 = __builtin_amdgcn_mfma_f32_16x16x32_bf16(a0, b0, acc00, 0, 0, 0);
    acc01 = __builtin_amdgcn_mfma_f32_16x16x32_bf16(a0, b1, acc01, 0, 0, 0);
    acc10 = __builtin_amdgcn_mfma_f32_16x16x32_bf16(a1, b0, acc10, 0, 0, 0);
    acc11 = __builtin_amdgcn_mfma_f32_16x16x32_bf16(a1, b1, acc11, 0, 0, 0);
  }
  const unsigned short* c0p = xaty + (size_t)(mw + lr) * 256 + kg * 8;
  const unsigned short* c1p = c0p + (size_t)16 * 256;
#pragma unroll
  for (int k = 0; k < 256; k += 32) {
    s16x8 a0 = *(const s16x8*)(c0p + k);
    s16x8 a1 = *(const s16x8*)(c1p + k);
    s16x8 b0 = *(const s16x8*)(b0p + 2048 + k);
    s16x8 b1 = *(const s16x8*)(b1p + 2048 + k);
    acc00 = __builtin_amdgcn_mfma_f32_16x16x32_bf16(a0, b0, acc00, 0, 0, 0);
    acc01 = __builtin_amdgcn_mfma_f32_16x16x32_bf16(a0, b1, acc01, 0, 0, 0);
    acc10 = __builtin_amdgcn_mfma_f32_16x16x32_bf16(a1, b0, acc10, 0, 0, 0);
    acc11 = __builtin_amdgcn_mfma_f32_16x16x32_bf16(a1, b1, acc11, 0, 0, 0);
  }
  int r0 = mwl + kg * 4;
  int c0 = nwl + lr;
#pragma unroll
  for (int fi = 0; fi < 2; ++fi)
#pragma unroll
    for (int fj = 0; fj < 2; ++fj) {
      f32x4 acc = (fi == 0) ? (fj == 0 ? acc00 : acc01) : (fj == 0 ? acc10 : acc11);
#pragma unroll
      for (int r = 0; r < 4; ++r) ld[r0 + fi * 16 + r][c0 + fj * 16] = acc[r];
    }
  __syncthreads();
  int row = threadIdx.x >> 2;
  int col0 = (threadIdx.x & 3) * 16;
  int b = blockIdx.y * 64 + row;
  int jbase = blockIdx.x * 16 + (threadIdx.x & 3) * 4;
  float4 cold = *(const float4*)(cbuf + (size_t)b * 1024 + jbase);
  float cn[4];
  unsigned short hb[4];
#pragma unroll
  for (int i = 0; i < 4; ++i) {
    float4 bs = *(const float4*)(bsum + (size_t)(jbase + i) * 4);
    float vi = ld[row][col0 + 4 * i + 0] + bs.x;
    float vf = ld[row][col0 + 4 * i + 1] + bs.y;
    float vg = ld[row][col0 + 4 * i + 2] + bs.z;
    float vo = ld[row][col0 + 4 * i + 3] + bs.w;
    float co = (i == 0) ? cold.x : (i == 1) ? cold.y : (i == 2) ? cold.z : cold.w;
    float ct = sigm(vf) * co + sigm(vi) * tanhf(vg);
    float ht = sigm(vo) * tanhf(ct);
    cn[i] = ct;
    hb[i] = f2b(ht);
  }
  *(float4*)(cbuf + (size_t)b * 1024 + jbase) = make_float4(cn[0], cn[1], cn[2], cn[3]);
  ushort4 h4 = make_ushort4(hb[0], hb[1], hb[2], hb[3]);
  *(ushort4*)(xout + (size_t)b * 2048 + 1024 + jbase) = h4;
  *(ushort4*)(a2 + (size_t)b * 2048 + jbase) = h4;
}

// ---------------- flash attention (single pass, nt loads, prefetch-2) -------
template <int BF16P>
__global__ __launch_bounds__(1024) void flash_attn(const unsigned short* __restrict__ srcb,
                                                   const float* __restrict__ srcf,
                                                   const float* __restrict__ q,
                                                   unsigned short* __restrict__ a2) {
  __shared__ unsigned short lctx[16][1024];
  __shared__ float lm[16], ldn[16], lsc[16];
  __shared__ float sDinv;
  int b = blockIdx.x;
  int wid = threadIdx.x >> 6, lane = threadIdx.x & 63;
  float qr[16];
  {
    const float4* qp = (const float4*)(q + (size_t)b * 1024 + lane * 16);
#pragma unroll
    for (int i = 0; i < 4; ++i) {
      float4 t = qp[i];
      qr[4 * i] = t.x; qr[4 * i + 1] = t.y; qr[4 * i + 2] = t.z; qr[4 * i + 3] = t.w;
    }
  }
  float m = -3e38f, d = 0.f;
  float ctx[16];
#pragma unroll
  for (int i = 0; i < 16; ++i) ctx[i] = 0.f;
  int s0 = wid * 32;

  if (BF16P) {
    const unsigned short* rb = srcb + (size_t)b * 524288 + lane * 16;
    s16x8 c0 = __builtin_nontemporal_load((const s16x8*)(rb + (size_t)s0 * 1024));
    s16x8 c1 = __builtin_nontemporal_load((const s16x8*)(rb + (size_t)s0 * 1024 + 8));
    s16x8 d0 = __builtin_nontemporal_load((const s16x8*)(rb + (size_t)(s0 + 1) * 1024));
    s16x8 d1 = __builtin_nontemporal_load((const s16x8*)(rb + (size_t)(s0 + 1) * 1024 + 8));
    for (int s = 0; s < 32; ++s) {
      int rn = s0 + s + 2;
      rn = rn > 511 ? 511 : rn;  // safe prefetch clamp
      s16x8 e0 = __builtin_nontemporal_load((const s16x8*)(rb + (size_t)rn * 1024));
      s16x8 e1 = __builtin_nontemporal_load((const s16x8*)(rb + (size_t)rn * 1024 + 8));
      float v[16];
#pragma unroll
      for (int i = 0; i < 8; ++i) {
        v[i] = b2f((unsigned short)c0[i]);
        v[8 + i] = b2f((unsigned short)c1[i]);
      }
      float sc = 0.f;
#pragma unroll
      for (int i = 0; i < 16; ++i) sc += v[i] * qr[i];
#pragma unroll
      for (int off = 1; off < 64; off <<= 1) sc += __shfl_xor(sc, off);
      float mn = fmaxf(m, sc);
      float scale = __expf(m - mn);
      float wgt = __expf(sc - mn);
      d = d * scale + wgt;
#pragma unroll
      for (int i = 0; i < 16; ++i) ctx[i] = ctx[i] * scale + wgt * v[i];
      m = mn;
      c0 = d0; c1 = d1; d0 = e0; d1 = e1;
    }
  } else {
    const float* rb = srcf + (size_t)b * 524288 + lane * 16;
    for (int s = 0; s < 32; ++s) {
      int r = s0 + s;
      float v[16];
#pragma unroll
      for (int i = 0; i < 4; ++i) {
        f32x4 t = __builtin_nontemporal_load((const f32x4*)(rb + (size_t)r * 1024 + 4 * i));
        v[4 * i] = t[0]; v[4 * i + 1] = t[1]; v[4 * i + 2] = t[2]; v[4 * i + 3] = t[3];
      }
      float sc = 0.f;
#pragma unroll
      for (int i = 0; i < 16; ++i) sc += v[i] * qr[i];
#pragma unroll
      for (int off = 1; off < 64; off <<= 1) sc += __shfl_xor(sc, off);
      float mn = fmaxf(m, sc);
      float scale = __expf(m - mn);
      float wgt = __expf(sc - mn);
      d = d * scale + wgt;
#pragma unroll
      for (int i = 0; i < 16; ++i) ctx[i] = ctx[i] * scale + wgt * v[i];
      m = mn;
    }
  }

#pragma unroll
  for (int i = 0; i < 16; ++i) lctx[wid][lane * 16 + i] = f2b(ctx[i]);
  if (lane == 0) { lm[wid] = m; ldn[wid] = d; }
  __syncthreads();
  if (threadIdx.x == 0) {
    float M = lm[0];
    for (int w2 = 1; w2 < 16; ++w2) M = fmaxf(M, lm[w2]);
    float D = 0.f;
    for (int w2 = 0; w2 < 16; ++w2) {
      float sc = __expf(lm[w2] - M);
      lsc[w2] = sc;
      D += sc * ldn[w2];
    }
    sDinv = 1.f / D;
  }
  __syncthreads();
  int e = threadIdx.x;
  float acc = 0.f;
#pragma unroll
  for (int w2 = 0; w2 < 16; ++w2) acc += lsc[w2] * b2f(lctx[w2][e]);
  a2[(size_t)b * 2048 + 1024 + e] = f2b(acc * sDinv);
}

// ---------------- standalone readout (final step only) ----------------------
__global__ __launch_bounds__(128) void readout(const float* __restrict__ att,
                                               const float* __restrict__ wqaT,
                                               const float* __restrict__ b_qa,
                                               const float* __restrict__ prod_emb,
                                               const float* __restrict__ prod_bias,
                                               float* __restrict__ out, int t) {
  __shared__ float s_att[1024], s_q2[128], s_log[97], s_red[2];
  int b = blockIdx.x;
  int tid = threadIdx.x;
  for (int i = tid; i < 1024; i += 128) s_att[i] = att[(size_t)b * 1024 + i];
  __syncthreads();
  float acc = b_qa[tid];
  for (int k = 0; k < 1024; ++k) acc += s_att[k] * wqaT[k * 128 + tid];
  s_q2[tid] = tanhf(acc);
  __syncthreads();
  if (tid < 97) {
    float a = prod_bias[tid];
    const float* pe = prod_emb + tid * 128;
    for (int k = 0; k < 128; ++k) a += s_q2[k] * pe[k];
    s_log[tid] = a;
  }
  __syncthreads();
  if (tid == 0) {
    float M = s_log[0];
    for (int k = 1; k < 97; ++k) M = fmaxf(M, s_log[k]);
    float D = 0.f;
    for (int k = 0; k < 97; ++k) D += __expf(s_log[k] - M);
    s_red[0] = M;
    s_red[1] = D;
  }
  __syncthreads();
  if (tid < 97)
    out[((size_t)t * 256 + b) * 97 + tid] = __expf(s_log[tid] - s_red[0]) / s_red[1];
}

// ---------------------------------------------------------------------------

extern "C" void kernel_launch(void* const* d_in, const int* in_sizes, int n_in,
                              void* d_out, int out_size, void* d_ws, size_t ws_size,
                              hipStream_t stream) {
  const float* src = (const float*)d_in[0];
  const int* action = (const int*)d_in[1];
  const int* type_ids = (const int*)d_in[2];
  const float* W_ih = (const float*)d_in[3];
  const float* b_ih = (const float*)d_in[4];
  const float* W_hh = (const float*)d_in[5];
  const float* b_hh = (const float*)d_in[6];
  const float* W_att = (const float*)d_in[7];
  const float* W_av = (const float*)d_in[8];
  const float* W_qa = (const float*)d_in[9];
  const float* b_qa = (const float*)d_in[10];
  const float* prod_emb = (const float*)d_in[11];
  const float* prod_bias = (const float*)d_in[12];
  const float* type_emb = (const float*)d_in[13];
  const float* W_init = (const float*)d_in[14];
  const float* b_init = (const float*)d_in[15];
  float* out = (float*)d_out;

  const size_t NEED_SMALL = 40910848ull;
  const size_t NEED_BIG = 309346304ull;
  bool big = ws_size >= NEED_BIG;
  if (!big && ws_size < NEED_SMALL) return;

  char* w = (char*)d_ws;
  size_t o = 0;
  unsigned short* wcat = (unsigned short*)(w + o); o += 18874368ull;
  unsigned short* wattT = (unsigned short*)(w + o); o += 2097152ull;
  unsigned short* wav = (unsigned short*)(w + o); o += 4194304ull;
  float* wqaT = (float*)(w + o); o += 524288ull;
  unsigned short* xaty = (unsigned short*)(w + o); o += 6291456ull;
  unsigned short* xstate0 = (unsigned short*)(w + o); o += 1048576ull;
  unsigned short* xstate1 = (unsigned short*)(w + o); o += 1048576ull;
  unsigned short* a2 = (unsigned short*)(w + o); o += 1048576ull;
  float* cbuf = (float*)(w + o); o += 1048576ull;
  float* qbuf = (float*)(w + o); o += 1048576ull;
  float* attf = (float*)(w + o); o += 1048576ull;
  unsigned short* pooledb = (unsigned short*)(w + o); o += 524288ull;
  unsigned short* winitb = (unsigned short*)(w + o); o += 2097152ull;
  float* bsum = (float*)(w + o); o += 16384ull;
  unsigned short* srcb = nullptr;
  if (big) { srcb = (unsigned short*)(w + o); o += 268435456ull; }

  // ---- prep ----
  if (big) pool_convert<1><<<1024, 256, 0, stream>>>(src, srcb, pooledb);
  else     pool_convert<0><<<1024, 256, 0, stream>>>(src, nullptr, pooledb);
  conv_wcat<<<36864, 256, 0, stream>>>(W_ih, W_hh, wcat);
  conv_bsum<<<16, 256, 0, stream>>>(b_ih, b_hh, bsum);
  conv_wattT<<<4096, 256, 0, stream>>>(W_att, wattT);
  conv_f2b<<<8192, 256, 0, stream>>>(W_av, wav, 2097152);
  conv_f2b<<<4096, 256, 0, stream>>>(W_init, winitb, 1048576);
  conv_wqaT<<<512, 256, 0, stream>>>(W_qa, wqaT);
  conv_xaty<<<12288, 256, 0, stream>>>(action, type_ids, prod_emb, type_emb, xaty);
  init0<<<1024, 256, 0, stream>>>(xstate0, cbuf);
  gemm_bt<2, 1024><<<dim3(16, 4), 256, 0, stream>>>(pooledb, 1024, winitb, 1024,
                                                    nullptr, 0, b_init, xstate0, 2048, 1024);

  // ---- 48 recurrent steps (4 nodes each; readout(t-1) rides gates(t)) ----
  for (int t = 0; t < 48; ++t) {
    const unsigned short* xin = (t & 1) ? xstate1 : xstate0;
    unsigned short* xout = (t & 1) ? xstate0 : xstate1;
    gates_fused<<<dim3(64, 5), 256, 0, stream>>>(xin, xaty + (size_t)t * 65536, wcat, bsum,
                                                 cbuf, xout, a2, attf, wqaT, b_qa, prod_emb,
                                                 prod_bias, out, t);
    gemm32<0, 1024><<<dim3(32, 8), 256, 0, stream>>>(a2, 2048, wattT, 1024, qbuf, 1024,
                                                     nullptr, 0, 0);
    if (big) flash_attn<1><<<256, 1024, 0, stream>>>(srcb, nullptr, qbuf, a2);
    else     flash_attn<0><<<256, 1024, 0, stream>>>(nullptr, src, qbuf, a2);
    gemm32<1, 2048><<<dim3(32, 8), 256, 0, stream>>>(a2, 2048, wav, 2048, attf, 1024,
                                                     xout, 2048, 0);
  }
  readout<<<256, 128, 0, stream>>>(attf, wqaT, b_qa, prod_emb, prod_bias, out, 47);
}